// Round 5
// baseline (363.986 us; speedup 1.0000x reference)
//
#include <hip/hip_runtime.h>
#include <math.h>

#define NN 64      // nodes
#define TT 256     // frames
#define FF 13      // input features
#define EE 4032    // edges (complete digraph)
#define PP 128     // pooling channels / GAT1 out
#define HH 128     // hidden

typedef float f32x4 __attribute__((ext_vector_type(4)));

__device__ __forceinline__ float wave_max64(float v) {
#pragma unroll
  for (int off = 32; off > 0; off >>= 1) v = fmaxf(v, __shfl_xor(v, off, 64));
  return v;
}
__device__ __forceinline__ float wave_sum64(float v) {
#pragma unroll
  for (int off = 32; off > 0; off >>= 1) v += __shfl_xor(v, off, 64);
  return v;
}
__device__ __forceinline__ float sigm(float x) { return 1.f / (1.f + __expf(-x)); }
__device__ __forceinline__ float tanh_fast(float x) { return 1.f - 2.f / (__expf(2.f * x) + 1.f); }

// ---------------------------------------------------------------------------
// Per-frame GNN: GAT1 (4 heads) -> relu -> GAT2 (1 head) -> relu ->
// attention-pool + max-pool -> embs[t][256]
// One block per frame, 512 threads (8 waves). Complete-graph edge indexing:
// edge (s->d) has id j = s*63 + (d<s ? d : d-1)  [np.nonzero(~eye) order].
// ---------------------------------------------------------------------------
__global__ __launch_bounds__(512, 2)
void gnn_kernel(const float* __restrict__ x, const float* __restrict__ ea_g,
                const float* __restrict__ W1, const float* __restrict__ a_src1,
                const float* __restrict__ a_dst1, const float* __restrict__ We1,
                const float* __restrict__ a_edge1, const float* __restrict__ b1,
                const float* __restrict__ W2, const float* __restrict__ a_src2,
                const float* __restrict__ a_dst2, const float* __restrict__ We2,
                const float* __restrict__ a_edge2, const float* __restrict__ b2,
                const float* __restrict__ Wg, const float* __restrict__ bg,
                float* __restrict__ embs)
{
  __shared__ float x_s[NN * FF];
  __shared__ float W1_s[FF * PP];
  __shared__ float ea_s[EE];
  __shared__ float hA_s[NN * PP];   // h1 (GAT1 projected), later p2 (GAT2 projected)
  __shared__ float hB_s[NN * PP];   // relu(GAT1 out), later relu(GAT2 out)
  __shared__ float as1_s[NN * 4];
  __shared__ float ad1_s[NN * 4];
  __shared__ float asrc1_s[PP], adst1_s[PP], asrc2_s[PP], adst2_s[PP];
  __shared__ float b1_s[PP], b2_s[PP], Wg_s[PP];
  __shared__ float as2_s[NN], ad2_s[NN];
  __shared__ float coef_s[8 * 64 * 4];
  __shared__ float wed_s[8];
  __shared__ float attn_s[NN];

  const int tid = threadIdx.x;
  const int t = blockIdx.x;
  const int wave = tid >> 6, lane = tid & 63;

  // stage inputs
  for (int i = tid; i < NN * FF; i += 512) x_s[i] = x[t * NN * FF + i];
  for (int i = tid; i < FF * PP; i += 512) W1_s[i] = W1[i];
  for (int i = tid; i < EE; i += 512) ea_s[i] = ea_g[t * EE + i];
  if (tid < PP) {
    asrc1_s[tid] = a_src1[tid]; adst1_s[tid] = a_dst1[tid];
    asrc2_s[tid] = a_src2[tid]; adst2_s[tid] = a_dst2[tid];
    b1_s[tid] = b1[tid]; b2_s[tid] = b2[tid]; Wg_s[tid] = Wg[tid];
  }
  if (tid >= 128 && tid < 132) {   // wedot1[h] = sum_c We1[h,c]*a_edge1[h,c]
    const int h = tid - 128;
    float acc = 0.f;
    for (int c = 0; c < 32; ++c) acc += We1[h * 32 + c] * a_edge1[h * 32 + c];
    wed_s[h] = acc;
  }
  if (tid == 132) {                // wedot2 = dot(We2, a_edge2)
    float acc = 0.f;
    for (int c = 0; c < 128; ++c) acc += We2[c] * a_edge2[c];
    wed_s[4] = acc;
  }
  __syncthreads();

  // h1 = x @ W1  -> hA  (8192 outputs, 16/thread)
  {
    const int c = tid & 127, ib = tid >> 7;
    for (int q = 0; q < 16; ++q) {
      const int i = ib * 16 + q;
      float acc = 0.f;
#pragma unroll
      for (int f = 0; f < FF; ++f) acc += x_s[i * FF + f] * W1_s[f * PP + c];
      hA_s[i * PP + c] = acc;
    }
  }
  __syncthreads();

  // per-node attention dots: as1[i][h], ad1[i][h]
  {
    const int half = tid >> 8;          // 0: src dots, 1: dst dots
    const int tt2 = tid & 255;
    const int i = tt2 >> 2, h = tt2 & 3;
    const float* aw = half ? adst1_s : asrc1_s;
    float acc = 0.f;
    for (int cc = 0; cc < 32; ++cc) {
      const int c = (cc + tid) & 31;    // rotation: LDS bank-conflict-free
      acc += hA_s[i * PP + h * 32 + c] * aw[h * 32 + c];
    }
    if (half) ad1_s[i * 4 + h] = acc; else as1_s[i * 4 + h] = acc;
  }
  __syncthreads();

  // GAT1 aggregation: each wave owns dst d = kk*8+wave; lanes 0..62 = srcs
  for (int kk = 0; kk < 8; ++kk) {
    const int d = kk * 8 + wave;
    {
      float a0, a1, a2, a3;
      if (lane < 63) {
        const int s = lane + (lane >= d ? 1 : 0);
        const int j = s * 63 + (d < s ? d : d - 1);
        const float ev = ea_s[j];
        a0 = as1_s[s * 4 + 0] + ad1_s[d * 4 + 0] + ev * wed_s[0];
        a1 = as1_s[s * 4 + 1] + ad1_s[d * 4 + 1] + ev * wed_s[1];
        a2 = as1_s[s * 4 + 2] + ad1_s[d * 4 + 2] + ev * wed_s[2];
        a3 = as1_s[s * 4 + 3] + ad1_s[d * 4 + 3] + ev * wed_s[3];
        a0 = a0 > 0.f ? a0 : 0.2f * a0;
        a1 = a1 > 0.f ? a1 : 0.2f * a1;
        a2 = a2 > 0.f ? a2 : 0.2f * a2;
        a3 = a3 > 0.f ? a3 : 0.2f * a3;
      } else { a0 = a1 = a2 = a3 = -1e30f; }
      const float m0 = wave_max64(a0), m1 = wave_max64(a1);
      const float m2 = wave_max64(a2), m3 = wave_max64(a3);
      const float p0 = (lane < 63) ? __expf(a0 - m0) : 0.f;
      const float p1 = (lane < 63) ? __expf(a1 - m1) : 0.f;
      const float p2 = (lane < 63) ? __expf(a2 - m2) : 0.f;
      const float p3 = (lane < 63) ? __expf(a3 - m3) : 0.f;
      const float s0 = wave_sum64(p0), s1 = wave_sum64(p1);
      const float s2 = wave_sum64(p2), s3 = wave_sum64(p3);
      float* cw = &coef_s[(wave * 64 + lane) * 4];
      cw[0] = p0 / (s0 + 1e-16f);
      cw[1] = p1 / (s1 + 1e-16f);
      cw[2] = p2 / (s2 + 1e-16f);
      cw[3] = p3 / (s3 + 1e-16f);
    }
    __syncthreads();
    {
      const int c0 = lane * 2;
      const int hh = c0 >> 5;
      float acc0 = 0.f, acc1 = 0.f;
      const float* cf = &coef_s[wave * 64 * 4 + hh];
      for (int s = 0; s < 63; ++s) {
        const int sn = s + (s >= d ? 1 : 0);
        const float cv = cf[s * 4];
        const float2 hv = *(const float2*)&hA_s[sn * PP + c0];
        acc0 += cv * hv.x; acc1 += cv * hv.y;
      }
      hB_s[d * PP + c0]     = fmaxf(acc0 + b1_s[c0], 0.f);
      hB_s[d * PP + c0 + 1] = fmaxf(acc1 + b1_s[c0 + 1], 0.f);
    }
    __syncthreads();
  }

  // p2 = relu(gat1) @ W2 -> hA (reuse; h1 dead).  W2 streamed from L2.
  {
    const int c = tid & 127, ib = tid >> 7;
    float acc[16];
#pragma unroll
    for (int q = 0; q < 16; ++q) acc[q] = 0.f;
    for (int f0 = 0; f0 < 128; f0 += 4) {
      const float w0 = W2[(f0 + 0) * PP + c];
      const float w1 = W2[(f0 + 1) * PP + c];
      const float w2 = W2[(f0 + 2) * PP + c];
      const float w3 = W2[(f0 + 3) * PP + c];
#pragma unroll
      for (int q = 0; q < 16; ++q) {
        const float4 hv = *(const float4*)&hB_s[(ib * 16 + q) * PP + f0];
        acc[q] += hv.x * w0 + hv.y * w1 + hv.z * w2 + hv.w * w3;
      }
    }
#pragma unroll
    for (int q = 0; q < 16; ++q) hA_s[(ib * 16 + q) * PP + c] = acc[q];
  }
  __syncthreads();

  // as2/ad2 node dots
  if (tid < 128) {
    const int i = tid >> 1, sel = tid & 1;
    const float* aw = sel ? adst2_s : asrc2_s;
    float acc = 0.f;
    for (int cc = 0; cc < 128; ++cc) {
      const int c = (cc + tid) & 127;
      acc += hA_s[i * PP + c] * aw[c];
    }
    if (sel) ad2_s[i] = acc; else as2_s[i] = acc;
  }
  __syncthreads();

  // GAT2 aggregation (1 head)
  for (int kk = 0; kk < 8; ++kk) {
    const int d = kk * 8 + wave;
    {
      float a;
      if (lane < 63) {
        const int s = lane + (lane >= d ? 1 : 0);
        const int j = s * 63 + (d < s ? d : d - 1);
        a = as2_s[s] + ad2_s[d] + ea_s[j] * wed_s[4];
        a = a > 0.f ? a : 0.2f * a;
      } else a = -1e30f;
      const float m = wave_max64(a);
      const float p = (lane < 63) ? __expf(a - m) : 0.f;
      const float ssum = wave_sum64(p);
      coef_s[wave * 64 + lane] = p / (ssum + 1e-16f);
    }
    __syncthreads();
    {
      const int c0 = lane * 2;
      float acc0 = 0.f, acc1 = 0.f;
      const float* cf = &coef_s[wave * 64];
      for (int s = 0; s < 63; ++s) {
        const int sn = s + (s >= d ? 1 : 0);
        const float cv = cf[s];
        const float2 hv = *(const float2*)&hA_s[sn * PP + c0];
        acc0 += cv * hv.x; acc1 += cv * hv.y;
      }
      hB_s[d * PP + c0]     = fmaxf(acc0 + b2_s[c0], 0.f);
      hB_s[d * PP + c0 + 1] = fmaxf(acc1 + b2_s[c0 + 1], 0.f);
    }
    __syncthreads();
  }

  // attention pooling (softmax over 64 nodes, wave 0) + max pooling
  if (tid < 64) {
    float acc = 0.f;
    for (int cc = 0; cc < 128; ++cc) {
      const int c = (cc + tid) & 127;
      acc += hB_s[tid * PP + c] * Wg_s[c];
    }
    const float logit = acc + bg[0];
    const float m = wave_max64(logit);
    const float p = __expf(logit - m);
    const float ssum = wave_sum64(p);
    attn_s[tid] = p / ssum;
  }
  __syncthreads();
  if (tid < 128) {
    const int c = tid;
    float acc = 0.f, mx = -1e30f;
    for (int i = 0; i < NN; ++i) {
      const float v = hB_s[i * PP + c];
      acc += attn_s[i] * v;
      mx = fmaxf(mx, v);
    }
    embs[t * 256 + c] = acc;
    embs[t * 256 + 128 + c] = mx;
  }
}

// ---------------------------------------------------------------------------
// Z[t][j] = Wih_f[j,:]·embs[t] + bih_f[j] + bhh_f[j]   (blocks 0..255)
// Zb[j]   = Wih_b[j,:]·embs[255] + bih_b[j] + bhh_b[j] (block 256)
// ---------------------------------------------------------------------------
__global__ __launch_bounds__(512, 2)
void zproj_kernel(const float* __restrict__ embs,
                  const float* __restrict__ Wih_f, const float* __restrict__ bih_f,
                  const float* __restrict__ bhh_f,
                  const float* __restrict__ Wih_b, const float* __restrict__ bih_b,
                  const float* __restrict__ bhh_b,
                  float* __restrict__ Z, float* __restrict__ Zb)
{
  __shared__ float e_s[256];
  const int t = blockIdx.x;
  const int j = threadIdx.x;
  const bool bwd = (t == TT);
  const int tsrc = bwd ? (TT - 1) : t;
  if (j < 256) e_s[j] = embs[tsrc * 256 + j];
  __syncthreads();
  const float* W = bwd ? Wih_b : Wih_f;
  float acc = bwd ? (bih_b[j] + bhh_b[j]) : (bih_f[j] + bhh_f[j]);
  const float4* Wr = (const float4*)(W + j * 256);
  const float4* er = (const float4*)e_s;
#pragma unroll 8
  for (int k = 0; k < 64; ++k) {
    const float4 w = Wr[k];
    const float4 e = er[k];
    acc += w.x * e.x + w.y * e.y + w.z * e.z + w.w * e.w;
  }
  if (bwd) Zb[j] = acc; else Z[t * 512 + j] = acc;
}

// ---------------------------------------------------------------------------
// Forward LSTM recurrence (256 steps, single block of 1024 threads).
// R1-R3 post-mortem (VGPR_Count 88/88/52 = weights never resident): the
// machine scheduler hoists ALL 16 ds_read_b128 h-loads to the top of the
// loop body; in-loop peak pressure = 64 w + 64 hv + misc > budget, so the
// RA splits the loop-invariant weight live-ranges to scratch. Fix:
// sched_barrier(0) fences every 4 ACCK group so at most 4 hv f32x4 are in
// flight -> peak ~96 < 128 budget. Weight loads volatile (exactly-once,
// cannot be sunk into the loop) + one keep-alive asm.
// ---------------------------------------------------------------------------
__global__ __launch_bounds__(1024, 4)
void lstm_kernel(const float* __restrict__ Z, const float* __restrict__ Zb,
                 const float* __restrict__ Whh_f,
                 const float* __restrict__ Wo, const float* __restrict__ bo,
                 float* __restrict__ out)
{
  __shared__ float h_s[128];
  __shared__ float p_s[1024];
  __shared__ float hb_s[128];
  __shared__ float red_s[16];
  const int tid = threadIdx.x;
  const int j = tid & 511;     // gate index
  const int s = tid >> 9;      // k-half (0: h[0..63], 1: h[64..127])

  const volatile f32x4* __restrict__ Wr =
      (const volatile f32x4*)(Whh_f + j * 128 + s * 64);
  f32x4 w0  = Wr[0],  w1  = Wr[1],  w2  = Wr[2],  w3  = Wr[3];
  f32x4 w4  = Wr[4],  w5  = Wr[5],  w6  = Wr[6],  w7  = Wr[7];
  f32x4 w8  = Wr[8],  w9  = Wr[9],  w10 = Wr[10], w11 = Wr[11];
  f32x4 w12 = Wr[12], w13 = Wr[13], w14 = Wr[14], w15 = Wr[15];
  asm volatile("" : "+v"(w0), "+v"(w1), "+v"(w2),  "+v"(w3),
                    "+v"(w4), "+v"(w5), "+v"(w6),  "+v"(w7),
                    "+v"(w8), "+v"(w9), "+v"(w10), "+v"(w11),
                    "+v"(w12), "+v"(w13), "+v"(w14), "+v"(w15));

  float c = 0.f;
  if (tid < 128) h_s[tid] = 0.f;
  __syncthreads();

  float zcur = (s == 0) ? Z[j] : 0.f;
  const f32x4* hr = (const f32x4*)h_s + s * 16;
  for (int t = 0; t < TT; ++t) {
    const float znext = (s == 0 && t < TT - 1) ? Z[(t + 1) * 512 + j] : 0.f;
    float a0 = zcur, a1 = 0.f, a2 = 0.f, a3 = 0.f;
#define ACCK(k, A) { const f32x4 hv = hr[k]; \
    A = fmaf(hv.x, w##k.x, A); A = fmaf(hv.y, w##k.y, A); \
    A = fmaf(hv.z, w##k.z, A); A = fmaf(hv.w, w##k.w, A); }
    ACCK(0, a0)  ACCK(1, a1)  ACCK(2, a2)  ACCK(3, a3)
    __builtin_amdgcn_sched_barrier(0);   // cap in-flight ds_reads at 4
    ACCK(4, a0)  ACCK(5, a1)  ACCK(6, a2)  ACCK(7, a3)
    __builtin_amdgcn_sched_barrier(0);
    ACCK(8, a0)  ACCK(9, a1)  ACCK(10, a2) ACCK(11, a3)
    __builtin_amdgcn_sched_barrier(0);
    ACCK(12, a0) ACCK(13, a1) ACCK(14, a2) ACCK(15, a3)
#undef ACCK
    p_s[tid] = (a0 + a1) + (a2 + a3);
    __syncthreads();
    if (tid < 128) {
      const float gi = p_s[tid]       + p_s[512 + tid];
      const float gf = p_s[128 + tid] + p_s[640 + tid];
      const float gg = p_s[256 + tid] + p_s[768 + tid];
      const float go = p_s[384 + tid] + p_s[896 + tid];
      c = sigm(gf) * c + sigm(gi) * tanh_fast(gg);
      h_s[tid] = sigm(go) * tanh_fast(c);
    }
    __syncthreads();
    zcur = znext;
  }

  // backward LSTM, first step only (h=c=0): elementwise on Zb
  if (tid < 128) {
    const float gi = Zb[tid], gg = Zb[256 + tid], go = Zb[384 + tid];
    const float cb = sigm(gi) * tanh_fast(gg);
    hb_s[tid] = sigm(go) * tanh_fast(cb);
  }
  __syncthreads();

  // out = sigmoid(concat(h_f, h_b) · Wo + bo)
  float v = 0.f;
  if (tid < 128) v = h_s[tid] * Wo[tid];
  else if (tid < 256) v = hb_s[tid - 128] * Wo[tid];
  v = wave_sum64(v);
  if ((tid & 63) == 0) red_s[tid >> 6] = v;
  __syncthreads();
  if (tid == 0) {
    float sum = bo[0];
#pragma unroll
    for (int k = 0; k < 16; ++k) sum += red_s[k];
    out[0] = 1.f / (1.f + __expf(-sum));
  }
}

extern "C" void kernel_launch(void* const* d_in, const int* in_sizes, int n_in,
                              void* d_out, int out_size, void* d_ws, size_t ws_size,
                              hipStream_t stream) {
  const float* x       = (const float*)d_in[0];
  // d_in[1] = edge_index (int32) — complete digraph, indexed analytically
  const float* ea      = (const float*)d_in[2];
  const float* W1      = (const float*)d_in[3];
  const float* a_src1  = (const float*)d_in[4];
  const float* a_dst1  = (const float*)d_in[5];
  const float* We1     = (const float*)d_in[6];
  const float* a_edge1 = (const float*)d_in[7];
  const float* b1      = (const float*)d_in[8];
  const float* W2      = (const float*)d_in[9];
  const float* a_src2  = (const float*)d_in[10];
  const float* a_dst2  = (const float*)d_in[11];
  const float* We2     = (const float*)d_in[12];
  const float* a_edge2 = (const float*)d_in[13];
  const float* b2      = (const float*)d_in[14];
  const float* Wg      = (const float*)d_in[15];
  const float* bg      = (const float*)d_in[16];
  const float* Wih_f   = (const float*)d_in[17];
  const float* Whh_f   = (const float*)d_in[18];
  const float* bih_f   = (const float*)d_in[19];
  const float* bhh_f   = (const float*)d_in[20];
  const float* Wih_b   = (const float*)d_in[21];
  // d_in[22] = Whh_b — unused: backward LSTM contributes only its first step (h=0)
  const float* bih_b   = (const float*)d_in[23];
  const float* bhh_b   = (const float*)d_in[24];
  const float* Wo      = (const float*)d_in[25];
  const float* bo      = (const float*)d_in[26];
  float* out = (float*)d_out;

  float* embs = (float*)d_ws;            // 256*256 floats
  float* Z    = embs + 256 * 256;        // 256*512 floats
  float* Zb   = Z + 256 * 512;           // 512 floats

  gnn_kernel<<<256, 512, 0, stream>>>(x, ea, W1, a_src1, a_dst1, We1, a_edge1, b1,
                                      W2, a_src2, a_dst2, We2, a_edge2, b2, Wg, bg, embs);
  zproj_kernel<<<257, 512, 0, stream>>>(embs, Wih_f, bih_f, bhh_f, Wih_b, bih_b, bhh_b, Z, Zb);
  lstm_kernel<<<1, 1024, 0, stream>>>(Z, Zb, Whh_f, Wo, bo, out);
}

// Round 6
// 363.447 us; speedup vs baseline: 1.0015x; 1.0015x over previous
//
#include <hip/hip_runtime.h>
#include <math.h>

#define NN 64      // nodes
#define TT 256     // frames
#define FF 13      // input features
#define EE 4032    // edges (complete digraph)
#define PP 128     // pooling channels / GAT1 out
#define HH 128     // hidden

typedef float f32x4 __attribute__((ext_vector_type(4)));

__device__ __forceinline__ float wave_max64(float v) {
#pragma unroll
  for (int off = 32; off > 0; off >>= 1) v = fmaxf(v, __shfl_xor(v, off, 64));
  return v;
}
__device__ __forceinline__ float wave_sum64(float v) {
#pragma unroll
  for (int off = 32; off > 0; off >>= 1) v += __shfl_xor(v, off, 64);
  return v;
}
__device__ __forceinline__ float sigm(float x) { return 1.f / (1.f + __expf(-x)); }
__device__ __forceinline__ float tanh_fast(float x) { return 1.f - 2.f / (__expf(2.f * x) + 1.f); }

// ---------------------------------------------------------------------------
// Per-frame GNN: GAT1 (4 heads) -> relu -> GAT2 (1 head) -> relu ->
// attention-pool + max-pool -> embs[t][256]
// One block per frame, 512 threads (8 waves). Complete-graph edge indexing:
// edge (s->d) has id j = s*63 + (d<s ? d : d-1)  [np.nonzero(~eye) order].
// ---------------------------------------------------------------------------
__global__ __launch_bounds__(512, 2)
void gnn_kernel(const float* __restrict__ x, const float* __restrict__ ea_g,
                const float* __restrict__ W1, const float* __restrict__ a_src1,
                const float* __restrict__ a_dst1, const float* __restrict__ We1,
                const float* __restrict__ a_edge1, const float* __restrict__ b1,
                const float* __restrict__ W2, const float* __restrict__ a_src2,
                const float* __restrict__ a_dst2, const float* __restrict__ We2,
                const float* __restrict__ a_edge2, const float* __restrict__ b2,
                const float* __restrict__ Wg, const float* __restrict__ bg,
                float* __restrict__ embs)
{
  __shared__ float x_s[NN * FF];
  __shared__ float W1_s[FF * PP];
  __shared__ float ea_s[EE];
  __shared__ float hA_s[NN * PP];   // h1 (GAT1 projected), later p2 (GAT2 projected)
  __shared__ float hB_s[NN * PP];   // relu(GAT1 out), later relu(GAT2 out)
  __shared__ float as1_s[NN * 4];
  __shared__ float ad1_s[NN * 4];
  __shared__ float asrc1_s[PP], adst1_s[PP], asrc2_s[PP], adst2_s[PP];
  __shared__ float b1_s[PP], b2_s[PP], Wg_s[PP];
  __shared__ float as2_s[NN], ad2_s[NN];
  __shared__ float coef_s[8 * 64 * 4];
  __shared__ float wed_s[8];
  __shared__ float attn_s[NN];

  const int tid = threadIdx.x;
  const int t = blockIdx.x;
  const int wave = tid >> 6, lane = tid & 63;

  // stage inputs
  for (int i = tid; i < NN * FF; i += 512) x_s[i] = x[t * NN * FF + i];
  for (int i = tid; i < FF * PP; i += 512) W1_s[i] = W1[i];
  for (int i = tid; i < EE; i += 512) ea_s[i] = ea_g[t * EE + i];
  if (tid < PP) {
    asrc1_s[tid] = a_src1[tid]; adst1_s[tid] = a_dst1[tid];
    asrc2_s[tid] = a_src2[tid]; adst2_s[tid] = a_dst2[tid];
    b1_s[tid] = b1[tid]; b2_s[tid] = b2[tid]; Wg_s[tid] = Wg[tid];
  }
  if (tid >= 128 && tid < 132) {   // wedot1[h] = sum_c We1[h,c]*a_edge1[h,c]
    const int h = tid - 128;
    float acc = 0.f;
    for (int c = 0; c < 32; ++c) acc += We1[h * 32 + c] * a_edge1[h * 32 + c];
    wed_s[h] = acc;
  }
  if (tid == 132) {                // wedot2 = dot(We2, a_edge2)
    float acc = 0.f;
    for (int c = 0; c < 128; ++c) acc += We2[c] * a_edge2[c];
    wed_s[4] = acc;
  }
  __syncthreads();

  // h1 = x @ W1  -> hA  (8192 outputs, 16/thread)
  {
    const int c = tid & 127, ib = tid >> 7;
    for (int q = 0; q < 16; ++q) {
      const int i = ib * 16 + q;
      float acc = 0.f;
#pragma unroll
      for (int f = 0; f < FF; ++f) acc += x_s[i * FF + f] * W1_s[f * PP + c];
      hA_s[i * PP + c] = acc;
    }
  }
  __syncthreads();

  // per-node attention dots: as1[i][h], ad1[i][h]
  {
    const int half = tid >> 8;          // 0: src dots, 1: dst dots
    const int tt2 = tid & 255;
    const int i = tt2 >> 2, h = tt2 & 3;
    const float* aw = half ? adst1_s : asrc1_s;
    float acc = 0.f;
    for (int cc = 0; cc < 32; ++cc) {
      const int c = (cc + tid) & 31;    // rotation: LDS bank-conflict-free
      acc += hA_s[i * PP + h * 32 + c] * aw[h * 32 + c];
    }
    if (half) ad1_s[i * 4 + h] = acc; else as1_s[i * 4 + h] = acc;
  }
  __syncthreads();

  // GAT1 aggregation: each wave owns dst d = kk*8+wave; lanes 0..62 = srcs
  for (int kk = 0; kk < 8; ++kk) {
    const int d = kk * 8 + wave;
    {
      float a0, a1, a2, a3;
      if (lane < 63) {
        const int s = lane + (lane >= d ? 1 : 0);
        const int j = s * 63 + (d < s ? d : d - 1);
        const float ev = ea_s[j];
        a0 = as1_s[s * 4 + 0] + ad1_s[d * 4 + 0] + ev * wed_s[0];
        a1 = as1_s[s * 4 + 1] + ad1_s[d * 4 + 1] + ev * wed_s[1];
        a2 = as1_s[s * 4 + 2] + ad1_s[d * 4 + 2] + ev * wed_s[2];
        a3 = as1_s[s * 4 + 3] + ad1_s[d * 4 + 3] + ev * wed_s[3];
        a0 = a0 > 0.f ? a0 : 0.2f * a0;
        a1 = a1 > 0.f ? a1 : 0.2f * a1;
        a2 = a2 > 0.f ? a2 : 0.2f * a2;
        a3 = a3 > 0.f ? a3 : 0.2f * a3;
      } else { a0 = a1 = a2 = a3 = -1e30f; }
      const float m0 = wave_max64(a0), m1 = wave_max64(a1);
      const float m2 = wave_max64(a2), m3 = wave_max64(a3);
      const float p0 = (lane < 63) ? __expf(a0 - m0) : 0.f;
      const float p1 = (lane < 63) ? __expf(a1 - m1) : 0.f;
      const float p2 = (lane < 63) ? __expf(a2 - m2) : 0.f;
      const float p3 = (lane < 63) ? __expf(a3 - m3) : 0.f;
      const float s0 = wave_sum64(p0), s1 = wave_sum64(p1);
      const float s2 = wave_sum64(p2), s3 = wave_sum64(p3);
      float* cw = &coef_s[(wave * 64 + lane) * 4];
      cw[0] = p0 / (s0 + 1e-16f);
      cw[1] = p1 / (s1 + 1e-16f);
      cw[2] = p2 / (s2 + 1e-16f);
      cw[3] = p3 / (s3 + 1e-16f);
    }
    __syncthreads();
    {
      const int c0 = lane * 2;
      const int hh = c0 >> 5;
      float acc0 = 0.f, acc1 = 0.f;
      const float* cf = &coef_s[wave * 64 * 4 + hh];
      for (int s = 0; s < 63; ++s) {
        const int sn = s + (s >= d ? 1 : 0);
        const float cv = cf[s * 4];
        const float2 hv = *(const float2*)&hA_s[sn * PP + c0];
        acc0 += cv * hv.x; acc1 += cv * hv.y;
      }
      hB_s[d * PP + c0]     = fmaxf(acc0 + b1_s[c0], 0.f);
      hB_s[d * PP + c0 + 1] = fmaxf(acc1 + b1_s[c0 + 1], 0.f);
    }
    __syncthreads();
  }

  // p2 = relu(gat1) @ W2 -> hA (reuse; h1 dead).  W2 streamed from L2.
  {
    const int c = tid & 127, ib = tid >> 7;
    float acc[16];
#pragma unroll
    for (int q = 0; q < 16; ++q) acc[q] = 0.f;
    for (int f0 = 0; f0 < 128; f0 += 4) {
      const float w0 = W2[(f0 + 0) * PP + c];
      const float w1 = W2[(f0 + 1) * PP + c];
      const float w2 = W2[(f0 + 2) * PP + c];
      const float w3 = W2[(f0 + 3) * PP + c];
#pragma unroll
      for (int q = 0; q < 16; ++q) {
        const float4 hv = *(const float4*)&hB_s[(ib * 16 + q) * PP + f0];
        acc[q] += hv.x * w0 + hv.y * w1 + hv.z * w2 + hv.w * w3;
      }
    }
#pragma unroll
    for (int q = 0; q < 16; ++q) hA_s[(ib * 16 + q) * PP + c] = acc[q];
  }
  __syncthreads();

  // as2/ad2 node dots
  if (tid < 128) {
    const int i = tid >> 1, sel = tid & 1;
    const float* aw = sel ? adst2_s : asrc2_s;
    float acc = 0.f;
    for (int cc = 0; cc < 128; ++cc) {
      const int c = (cc + tid) & 127;
      acc += hA_s[i * PP + c] * aw[c];
    }
    if (sel) ad2_s[i] = acc; else as2_s[i] = acc;
  }
  __syncthreads();

  // GAT2 aggregation (1 head)
  for (int kk = 0; kk < 8; ++kk) {
    const int d = kk * 8 + wave;
    {
      float a;
      if (lane < 63) {
        const int s = lane + (lane >= d ? 1 : 0);
        const int j = s * 63 + (d < s ? d : d - 1);
        a = as2_s[s] + ad2_s[d] + ea_s[j] * wed_s[4];
        a = a > 0.f ? a : 0.2f * a;
      } else a = -1e30f;
      const float m = wave_max64(a);
      const float p = (lane < 63) ? __expf(a - m) : 0.f;
      const float ssum = wave_sum64(p);
      coef_s[wave * 64 + lane] = p / (ssum + 1e-16f);
    }
    __syncthreads();
    {
      const int c0 = lane * 2;
      float acc0 = 0.f, acc1 = 0.f;
      const float* cf = &coef_s[wave * 64];
      for (int s = 0; s < 63; ++s) {
        const int sn = s + (s >= d ? 1 : 0);
        const float cv = cf[s];
        const float2 hv = *(const float2*)&hA_s[sn * PP + c0];
        acc0 += cv * hv.x; acc1 += cv * hv.y;
      }
      hB_s[d * PP + c0]     = fmaxf(acc0 + b2_s[c0], 0.f);
      hB_s[d * PP + c0 + 1] = fmaxf(acc1 + b2_s[c0 + 1], 0.f);
    }
    __syncthreads();
  }

  // attention pooling (softmax over 64 nodes, wave 0) + max pooling
  if (tid < 64) {
    float acc = 0.f;
    for (int cc = 0; cc < 128; ++cc) {
      const int c = (cc + tid) & 127;
      acc += hB_s[tid * PP + c] * Wg_s[c];
    }
    const float logit = acc + bg[0];
    const float m = wave_max64(logit);
    const float p = __expf(logit - m);
    const float ssum = wave_sum64(p);
    attn_s[tid] = p / ssum;
  }
  __syncthreads();
  if (tid < 128) {
    const int c = tid;
    float acc = 0.f, mx = -1e30f;
    for (int i = 0; i < NN; ++i) {
      const float v = hB_s[i * PP + c];
      acc += attn_s[i] * v;
      mx = fmaxf(mx, v);
    }
    embs[t * 256 + c] = acc;
    embs[t * 256 + 128 + c] = mx;
  }
}

// ---------------------------------------------------------------------------
// Z[t][j] = Wih_f[j,:]·embs[t] + bih_f[j] + bhh_f[j]   (blocks 0..255)
// Zb[j]   = Wih_b[j,:]·embs[255] + bih_b[j] + bhh_b[j] (block 256)
// ---------------------------------------------------------------------------
__global__ __launch_bounds__(512, 2)
void zproj_kernel(const float* __restrict__ embs,
                  const float* __restrict__ Wih_f, const float* __restrict__ bih_f,
                  const float* __restrict__ bhh_f,
                  const float* __restrict__ Wih_b, const float* __restrict__ bih_b,
                  const float* __restrict__ bhh_b,
                  float* __restrict__ Z, float* __restrict__ Zb)
{
  __shared__ float e_s[256];
  const int t = blockIdx.x;
  const int j = threadIdx.x;
  const bool bwd = (t == TT);
  const int tsrc = bwd ? (TT - 1) : t;
  if (j < 256) e_s[j] = embs[tsrc * 256 + j];
  __syncthreads();
  const float* W = bwd ? Wih_b : Wih_f;
  float acc = bwd ? (bih_b[j] + bhh_b[j]) : (bih_f[j] + bhh_f[j]);
  const float4* Wr = (const float4*)(W + j * 256);
  const float4* er = (const float4*)e_s;
#pragma unroll 8
  for (int k = 0; k < 64; ++k) {
    const float4 w = Wr[k];
    const float4 e = er[k];
    acc += w.x * e.x + w.y * e.y + w.z * e.z + w.w * e.w;
  }
  if (bwd) Zb[j] = acc; else Z[t * 512 + j] = acc;
}

// ---------------------------------------------------------------------------
// Forward LSTM recurrence (256 steps, single block of 1024 threads).
// R1-R5 post-mortem: every spill came from the backend's OCCUPANCY
// heuristic, not true pressure. R5's VGPR_Count=64 is exactly the
// 8-waves/EU boundary: __launch_bounds__(.,4) only guarantees >=4
// waves/EU (VGPR<=128); the allocator still chased 8 waves/EU (<=64
// VGPR) and paid scratch for it (WRITE_SIZE jumped to 8KB). Since this
// kernel is ONE block on ONE CU, extra occupancy is worthless.
// amdgpu_waves_per_eu(4,4) clamps min=max=4 -> budget 128, demand ~94
// (64 w + <=16 in-flight hv via sched_barrier caps + misc) -> no spill.
// ---------------------------------------------------------------------------
__global__ __launch_bounds__(1024)
__attribute__((amdgpu_waves_per_eu(4, 4)))
void lstm_kernel(const float* __restrict__ Z, const float* __restrict__ Zb,
                 const float* __restrict__ Whh_f,
                 const float* __restrict__ Wo, const float* __restrict__ bo,
                 float* __restrict__ out)
{
  __shared__ float h_s[128];
  __shared__ float p_s[1024];
  __shared__ float hb_s[128];
  __shared__ float red_s[16];
  const int tid = threadIdx.x;
  const int j = tid & 511;     // gate index
  const int s = tid >> 9;      // k-half (0: h[0..63], 1: h[64..127])

  const volatile f32x4* __restrict__ Wr =
      (const volatile f32x4*)(Whh_f + j * 128 + s * 64);
  f32x4 w0  = Wr[0],  w1  = Wr[1],  w2  = Wr[2],  w3  = Wr[3];
  f32x4 w4  = Wr[4],  w5  = Wr[5],  w6  = Wr[6],  w7  = Wr[7];
  f32x4 w8  = Wr[8],  w9  = Wr[9],  w10 = Wr[10], w11 = Wr[11];
  f32x4 w12 = Wr[12], w13 = Wr[13], w14 = Wr[14], w15 = Wr[15];
  asm volatile("" : "+v"(w0), "+v"(w1), "+v"(w2),  "+v"(w3),
                    "+v"(w4), "+v"(w5), "+v"(w6),  "+v"(w7),
                    "+v"(w8), "+v"(w9), "+v"(w10), "+v"(w11),
                    "+v"(w12), "+v"(w13), "+v"(w14), "+v"(w15));

  float c = 0.f;
  if (tid < 128) h_s[tid] = 0.f;
  __syncthreads();

  float zcur = (s == 0) ? Z[j] : 0.f;
  const f32x4* hr = (const f32x4*)h_s + s * 16;
  for (int t = 0; t < TT; ++t) {
    const float znext = (s == 0 && t < TT - 1) ? Z[(t + 1) * 512 + j] : 0.f;
    float a0 = zcur, a1 = 0.f, a2 = 0.f, a3 = 0.f;
#define ACCK(k, A) { const f32x4 hv = hr[k]; \
    A = fmaf(hv.x, w##k.x, A); A = fmaf(hv.y, w##k.y, A); \
    A = fmaf(hv.z, w##k.z, A); A = fmaf(hv.w, w##k.w, A); }
    ACCK(0, a0)  ACCK(1, a1)  ACCK(2, a2)  ACCK(3, a3)
    __builtin_amdgcn_sched_barrier(0);   // cap in-flight ds_reads at 4
    ACCK(4, a0)  ACCK(5, a1)  ACCK(6, a2)  ACCK(7, a3)
    __builtin_amdgcn_sched_barrier(0);
    ACCK(8, a0)  ACCK(9, a1)  ACCK(10, a2) ACCK(11, a3)
    __builtin_amdgcn_sched_barrier(0);
    ACCK(12, a0) ACCK(13, a1) ACCK(14, a2) ACCK(15, a3)
#undef ACCK
    p_s[tid] = (a0 + a1) + (a2 + a3);
    __syncthreads();
    if (tid < 128) {
      const float gi = p_s[tid]       + p_s[512 + tid];
      const float gf = p_s[128 + tid] + p_s[640 + tid];
      const float gg = p_s[256 + tid] + p_s[768 + tid];
      const float go = p_s[384 + tid] + p_s[896 + tid];
      c = sigm(gf) * c + sigm(gi) * tanh_fast(gg);
      h_s[tid] = sigm(go) * tanh_fast(c);
    }
    __syncthreads();
    zcur = znext;
  }

  // backward LSTM, first step only (h=c=0): elementwise on Zb
  if (tid < 128) {
    const float gi = Zb[tid], gg = Zb[256 + tid], go = Zb[384 + tid];
    const float cb = sigm(gi) * tanh_fast(gg);
    hb_s[tid] = sigm(go) * tanh_fast(cb);
  }
  __syncthreads();

  // out = sigmoid(concat(h_f, h_b) · Wo + bo)
  float v = 0.f;
  if (tid < 128) v = h_s[tid] * Wo[tid];
  else if (tid < 256) v = hb_s[tid - 128] * Wo[tid];
  v = wave_sum64(v);
  if ((tid & 63) == 0) red_s[tid >> 6] = v;
  __syncthreads();
  if (tid == 0) {
    float sum = bo[0];
#pragma unroll
    for (int k = 0; k < 16; ++k) sum += red_s[k];
    out[0] = 1.f / (1.f + __expf(-sum));
  }
}

extern "C" void kernel_launch(void* const* d_in, const int* in_sizes, int n_in,
                              void* d_out, int out_size, void* d_ws, size_t ws_size,
                              hipStream_t stream) {
  const float* x       = (const float*)d_in[0];
  // d_in[1] = edge_index (int32) — complete digraph, indexed analytically
  const float* ea      = (const float*)d_in[2];
  const float* W1      = (const float*)d_in[3];
  const float* a_src1  = (const float*)d_in[4];
  const float* a_dst1  = (const float*)d_in[5];
  const float* We1     = (const float*)d_in[6];
  const float* a_edge1 = (const float*)d_in[7];
  const float* b1      = (const float*)d_in[8];
  const float* W2      = (const float*)d_in[9];
  const float* a_src2  = (const float*)d_in[10];
  const float* a_dst2  = (const float*)d_in[11];
  const float* We2     = (const float*)d_in[12];
  const float* a_edge2 = (const float*)d_in[13];
  const float* b2      = (const float*)d_in[14];
  const float* Wg      = (const float*)d_in[15];
  const float* bg      = (const float*)d_in[16];
  const float* Wih_f   = (const float*)d_in[17];
  const float* Whh_f   = (const float*)d_in[18];
  const float* bih_f   = (const float*)d_in[19];
  const float* bhh_f   = (const float*)d_in[20];
  const float* Wih_b   = (const float*)d_in[21];
  // d_in[22] = Whh_b — unused: backward LSTM contributes only its first step (h=0)
  const float* bih_b   = (const float*)d_in[23];
  const float* bhh_b   = (const float*)d_in[24];
  const float* Wo      = (const float*)d_in[25];
  const float* bo      = (const float*)d_in[26];
  float* out = (float*)d_out;

  float* embs = (float*)d_ws;            // 256*256 floats
  float* Z    = embs + 256 * 256;        // 256*512 floats
  float* Zb   = Z + 256 * 512;           // 512 floats

  gnn_kernel<<<256, 512, 0, stream>>>(x, ea, W1, a_src1, a_dst1, We1, a_edge1, b1,
                                      W2, a_src2, a_dst2, We2, a_edge2, b2, Wg, bg, embs);
  zproj_kernel<<<257, 512, 0, stream>>>(embs, Wih_f, bih_f, bhh_f, Wih_b, bih_b, bhh_b, Z, Zb);
  lstm_kernel<<<1, 1024, 0, stream>>>(Z, Zb, Whh_f, Wo, bo, out);
}

// Round 7
// 304.633 us; speedup vs baseline: 1.1948x; 1.1931x over previous
//
#include <hip/hip_runtime.h>
#include <math.h>

#define NN 64      // nodes
#define TT 256     // frames
#define FF 13      // input features
#define EE 4032    // edges (complete digraph)
#define PP 128     // pooling channels / GAT1 out
#define HH 128     // hidden

typedef float f32x4 __attribute__((ext_vector_type(4)));
typedef _Float16 f16x2 __attribute__((ext_vector_type(2)));
typedef unsigned u32x4 __attribute__((ext_vector_type(4)));

__device__ __forceinline__ float wave_max64(float v) {
#pragma unroll
  for (int off = 32; off > 0; off >>= 1) v = fmaxf(v, __shfl_xor(v, off, 64));
  return v;
}
__device__ __forceinline__ float wave_sum64(float v) {
#pragma unroll
  for (int off = 32; off > 0; off >>= 1) v += __shfl_xor(v, off, 64);
  return v;
}
__device__ __forceinline__ float sigm(float x) { return 1.f / (1.f + __expf(-x)); }
__device__ __forceinline__ float tanh_fast(float x) { return 1.f - 2.f / (__expf(2.f * x) + 1.f); }

// pack two fp32 -> one dword of two f16 (round-toward-zero HW op)
__device__ __forceinline__ unsigned pk_f16(float lo, float hi) {
  unsigned u;
  asm("v_cvt_pkrtz_f16_f32 %0, %1, %2" : "=v"(u) : "v"(lo), "v"(hi));
  return u;
}

// fp32 += dot2(f16x2, f16x2)  -- v_dot2_f32_f16 (fp32 accumulate)
__device__ __forceinline__ float fdot2u(unsigned h, unsigned w, float acc) {
#if __has_builtin(__builtin_amdgcn_fdot2)
  return __builtin_amdgcn_fdot2(__builtin_bit_cast(f16x2, h),
                                __builtin_bit_cast(f16x2, w), acc, false);
#else
  const f16x2 a = __builtin_bit_cast(f16x2, h);
  const f16x2 b = __builtin_bit_cast(f16x2, w);
  return acc + (float)a.x * (float)b.x + (float)a.y * (float)b.y;
#endif
}

// ---------------------------------------------------------------------------
// Per-frame GNN: GAT1 (4 heads) -> relu -> GAT2 (1 head) -> relu ->
// attention-pool + max-pool -> embs[t][256]
// One block per frame, 512 threads (8 waves). Complete-graph edge indexing:
// edge (s->d) has id j = s*63 + (d<s ? d : d-1)  [np.nonzero(~eye) order].
// ---------------------------------------------------------------------------
__global__ __launch_bounds__(512, 2)
void gnn_kernel(const float* __restrict__ x, const float* __restrict__ ea_g,
                const float* __restrict__ W1, const float* __restrict__ a_src1,
                const float* __restrict__ a_dst1, const float* __restrict__ We1,
                const float* __restrict__ a_edge1, const float* __restrict__ b1,
                const float* __restrict__ W2, const float* __restrict__ a_src2,
                const float* __restrict__ a_dst2, const float* __restrict__ We2,
                const float* __restrict__ a_edge2, const float* __restrict__ b2,
                const float* __restrict__ Wg, const float* __restrict__ bg,
                float* __restrict__ embs)
{
  __shared__ float x_s[NN * FF];
  __shared__ float W1_s[FF * PP];
  __shared__ float ea_s[EE];
  __shared__ float hA_s[NN * PP];   // h1 (GAT1 projected), later p2 (GAT2 projected)
  __shared__ float hB_s[NN * PP];   // relu(GAT1 out), later relu(GAT2 out)
  __shared__ float as1_s[NN * 4];
  __shared__ float ad1_s[NN * 4];
  __shared__ float asrc1_s[PP], adst1_s[PP], asrc2_s[PP], adst2_s[PP];
  __shared__ float b1_s[PP], b2_s[PP], Wg_s[PP];
  __shared__ float as2_s[NN], ad2_s[NN];
  __shared__ float coef_s[8 * 64 * 4];
  __shared__ float wed_s[8];
  __shared__ float attn_s[NN];

  const int tid = threadIdx.x;
  const int t = blockIdx.x;
  const int wave = tid >> 6, lane = tid & 63;

  // stage inputs
  for (int i = tid; i < NN * FF; i += 512) x_s[i] = x[t * NN * FF + i];
  for (int i = tid; i < FF * PP; i += 512) W1_s[i] = W1[i];
  for (int i = tid; i < EE; i += 512) ea_s[i] = ea_g[t * EE + i];
  if (tid < PP) {
    asrc1_s[tid] = a_src1[tid]; adst1_s[tid] = a_dst1[tid];
    asrc2_s[tid] = a_src2[tid]; adst2_s[tid] = a_dst2[tid];
    b1_s[tid] = b1[tid]; b2_s[tid] = b2[tid]; Wg_s[tid] = Wg[tid];
  }
  if (tid >= 128 && tid < 132) {   // wedot1[h] = sum_c We1[h,c]*a_edge1[h,c]
    const int h = tid - 128;
    float acc = 0.f;
    for (int c = 0; c < 32; ++c) acc += We1[h * 32 + c] * a_edge1[h * 32 + c];
    wed_s[h] = acc;
  }
  if (tid == 132) {                // wedot2 = dot(We2, a_edge2)
    float acc = 0.f;
    for (int c = 0; c < 128; ++c) acc += We2[c] * a_edge2[c];
    wed_s[4] = acc;
  }
  __syncthreads();

  // h1 = x @ W1  -> hA  (8192 outputs, 16/thread)
  {
    const int c = tid & 127, ib = tid >> 7;
    for (int q = 0; q < 16; ++q) {
      const int i = ib * 16 + q;
      float acc = 0.f;
#pragma unroll
      for (int f = 0; f < FF; ++f) acc += x_s[i * FF + f] * W1_s[f * PP + c];
      hA_s[i * PP + c] = acc;
    }
  }
  __syncthreads();

  // per-node attention dots: as1[i][h], ad1[i][h]
  {
    const int half = tid >> 8;          // 0: src dots, 1: dst dots
    const int tt2 = tid & 255;
    const int i = tt2 >> 2, h = tt2 & 3;
    const float* aw = half ? adst1_s : asrc1_s;
    float acc = 0.f;
    for (int cc = 0; cc < 32; ++cc) {
      const int c = (cc + tid) & 31;    // rotation: LDS bank-conflict-free
      acc += hA_s[i * PP + h * 32 + c] * aw[h * 32 + c];
    }
    if (half) ad1_s[i * 4 + h] = acc; else as1_s[i * 4 + h] = acc;
  }
  __syncthreads();

  // GAT1 aggregation: each wave owns dst d = kk*8+wave; lanes 0..62 = srcs
  for (int kk = 0; kk < 8; ++kk) {
    const int d = kk * 8 + wave;
    {
      float a0, a1, a2, a3;
      if (lane < 63) {
        const int s = lane + (lane >= d ? 1 : 0);
        const int j = s * 63 + (d < s ? d : d - 1);
        const float ev = ea_s[j];
        a0 = as1_s[s * 4 + 0] + ad1_s[d * 4 + 0] + ev * wed_s[0];
        a1 = as1_s[s * 4 + 1] + ad1_s[d * 4 + 1] + ev * wed_s[1];
        a2 = as1_s[s * 4 + 2] + ad1_s[d * 4 + 2] + ev * wed_s[2];
        a3 = as1_s[s * 4 + 3] + ad1_s[d * 4 + 3] + ev * wed_s[3];
        a0 = a0 > 0.f ? a0 : 0.2f * a0;
        a1 = a1 > 0.f ? a1 : 0.2f * a1;
        a2 = a2 > 0.f ? a2 : 0.2f * a2;
        a3 = a3 > 0.f ? a3 : 0.2f * a3;
      } else { a0 = a1 = a2 = a3 = -1e30f; }
      const float m0 = wave_max64(a0), m1 = wave_max64(a1);
      const float m2 = wave_max64(a2), m3 = wave_max64(a3);
      const float p0 = (lane < 63) ? __expf(a0 - m0) : 0.f;
      const float p1 = (lane < 63) ? __expf(a1 - m1) : 0.f;
      const float p2 = (lane < 63) ? __expf(a2 - m2) : 0.f;
      const float p3 = (lane < 63) ? __expf(a3 - m3) : 0.f;
      const float s0 = wave_sum64(p0), s1 = wave_sum64(p1);
      const float s2 = wave_sum64(p2), s3 = wave_sum64(p3);
      float* cw = &coef_s[(wave * 64 + lane) * 4];
      cw[0] = p0 / (s0 + 1e-16f);
      cw[1] = p1 / (s1 + 1e-16f);
      cw[2] = p2 / (s2 + 1e-16f);
      cw[3] = p3 / (s3 + 1e-16f);
    }
    __syncthreads();
    {
      const int c0 = lane * 2;
      const int hh = c0 >> 5;
      float acc0 = 0.f, acc1 = 0.f;
      const float* cf = &coef_s[wave * 64 * 4 + hh];
      for (int s = 0; s < 63; ++s) {
        const int sn = s + (s >= d ? 1 : 0);
        const float cv = cf[s * 4];
        const float2 hv = *(const float2*)&hA_s[sn * PP + c0];
        acc0 += cv * hv.x; acc1 += cv * hv.y;
      }
      hB_s[d * PP + c0]     = fmaxf(acc0 + b1_s[c0], 0.f);
      hB_s[d * PP + c0 + 1] = fmaxf(acc1 + b1_s[c0 + 1], 0.f);
    }
    __syncthreads();
  }

  // p2 = relu(gat1) @ W2 -> hA (reuse; h1 dead).  W2 streamed from L2.
  {
    const int c = tid & 127, ib = tid >> 7;
    float acc[16];
#pragma unroll
    for (int q = 0; q < 16; ++q) acc[q] = 0.f;
    for (int f0 = 0; f0 < 128; f0 += 4) {
      const float w0 = W2[(f0 + 0) * PP + c];
      const float w1 = W2[(f0 + 1) * PP + c];
      const float w2 = W2[(f0 + 2) * PP + c];
      const float w3 = W2[(f0 + 3) * PP + c];
#pragma unroll
      for (int q = 0; q < 16; ++q) {
        const float4 hv = *(const float4*)&hB_s[(ib * 16 + q) * PP + f0];
        acc[q] += hv.x * w0 + hv.y * w1 + hv.z * w2 + hv.w * w3;
      }
    }
#pragma unroll
    for (int q = 0; q < 16; ++q) hA_s[(ib * 16 + q) * PP + c] = acc[q];
  }
  __syncthreads();

  // as2/ad2 node dots
  if (tid < 128) {
    const int i = tid >> 1, sel = tid & 1;
    const float* aw = sel ? adst2_s : asrc2_s;
    float acc = 0.f;
    for (int cc = 0; cc < 128; ++cc) {
      const int c = (cc + tid) & 127;
      acc += hA_s[i * PP + c] * aw[c];
    }
    if (sel) ad2_s[i] = acc; else as2_s[i] = acc;
  }
  __syncthreads();

  // GAT2 aggregation (1 head)
  for (int kk = 0; kk < 8; ++kk) {
    const int d = kk * 8 + wave;
    {
      float a;
      if (lane < 63) {
        const int s = lane + (lane >= d ? 1 : 0);
        const int j = s * 63 + (d < s ? d : d - 1);
        a = as2_s[s] + ad2_s[d] + ea_s[j] * wed_s[4];
        a = a > 0.f ? a : 0.2f * a;
      } else a = -1e30f;
      const float m = wave_max64(a);
      const float p = (lane < 63) ? __expf(a - m) : 0.f;
      const float ssum = wave_sum64(p);
      coef_s[wave * 64 + lane] = p / (ssum + 1e-16f);
    }
    __syncthreads();
    {
      const int c0 = lane * 2;
      float acc0 = 0.f, acc1 = 0.f;
      const float* cf = &coef_s[wave * 64];
      for (int s = 0; s < 63; ++s) {
        const int sn = s + (s >= d ? 1 : 0);
        const float cv = cf[s];
        const float2 hv = *(const float2*)&hA_s[sn * PP + c0];
        acc0 += cv * hv.x; acc1 += cv * hv.y;
      }
      hB_s[d * PP + c0]     = fmaxf(acc0 + b2_s[c0], 0.f);
      hB_s[d * PP + c0 + 1] = fmaxf(acc1 + b2_s[c0 + 1], 0.f);
    }
    __syncthreads();
  }

  // attention pooling (softmax over 64 nodes, wave 0) + max pooling
  if (tid < 64) {
    float acc = 0.f;
    for (int cc = 0; cc < 128; ++cc) {
      const int c = (cc + tid) & 127;
      acc += hB_s[tid * PP + c] * Wg_s[c];
    }
    const float logit = acc + bg[0];
    const float m = wave_max64(logit);
    const float p = __expf(logit - m);
    const float ssum = wave_sum64(p);
    attn_s[tid] = p / ssum;
  }
  __syncthreads();
  if (tid < 128) {
    const int c = tid;
    float acc = 0.f, mx = -1e30f;
    for (int i = 0; i < NN; ++i) {
      const float v = hB_s[i * PP + c];
      acc += attn_s[i] * v;
      mx = fmaxf(mx, v);
    }
    embs[t * 256 + c] = acc;
    embs[t * 256 + 128 + c] = mx;
  }
}

// ---------------------------------------------------------------------------
// Z[t][j] = Wih_f[j,:]·embs[t] + bih_f[j] + bhh_f[j]   (blocks 0..255)
// Zb[j]   = Wih_b[j,:]·embs[255] + bih_b[j] + bhh_b[j] (block 256)
// ---------------------------------------------------------------------------
__global__ __launch_bounds__(512, 2)
void zproj_kernel(const float* __restrict__ embs,
                  const float* __restrict__ Wih_f, const float* __restrict__ bih_f,
                  const float* __restrict__ bhh_f,
                  const float* __restrict__ Wih_b, const float* __restrict__ bih_b,
                  const float* __restrict__ bhh_b,
                  float* __restrict__ Z, float* __restrict__ Zb)
{
  __shared__ float e_s[256];
  const int t = blockIdx.x;
  const int j = threadIdx.x;
  const bool bwd = (t == TT);
  const int tsrc = bwd ? (TT - 1) : t;
  if (j < 256) e_s[j] = embs[tsrc * 256 + j];
  __syncthreads();
  const float* W = bwd ? Wih_b : Wih_f;
  float acc = bwd ? (bih_b[j] + bhh_b[j]) : (bih_f[j] + bhh_f[j]);
  const float4* Wr = (const float4*)(W + j * 256);
  const float4* er = (const float4*)e_s;
#pragma unroll 8
  for (int k = 0; k < 64; ++k) {
    const float4 w = Wr[k];
    const float4 e = er[k];
    acc += w.x * e.x + w.y * e.y + w.z * e.z + w.w * e.w;
  }
  if (bwd) Zb[j] = acc; else Z[t * 512 + j] = acc;
}

// ---------------------------------------------------------------------------
// Forward LSTM recurrence (256 steps, single block of 1024 threads).
// R1-R6 post-mortem: the backend refuses >64 VGPRs for this kernel (it
// budgets for 2 workgroups/CU) and spills fp32 weights to scratch no
// matter how residency is phrased. New approach: FIT the 64-VGPR budget.
// Weights held as packed f16 pairs: 64 weights/thread = 32 dwords = 32
// VGPRs; dot via v_dot2_f32_f16 (fp32 accumulate, 2 MAC/instr). h is
// repacked to f16x2 in LDS each step by the gate threads. Demand ~55 <
// 64 -> no spill pressure at the allocator's own occupancy target.
// Numerics: only the h->gate matvec is f16 (11 mantissa bits); Z, gate
// math, accumulators all fp32. Error per step ~5e-4, contractive.
// ---------------------------------------------------------------------------
__global__ __launch_bounds__(1024)
void lstm_kernel(const float* __restrict__ Z, const float* __restrict__ Zb,
                 const float* __restrict__ Whh_f,
                 const float* __restrict__ Wo, const float* __restrict__ bo,
                 float* __restrict__ out)
{
  __shared__ float h_s[128];
  __shared__ __align__(16) unsigned h16_s[64];  // h packed as 64 f16x2 dwords
  __shared__ float p_s[1024];
  __shared__ float hb_s[128];
  __shared__ float red_s[16];
  const int tid = threadIdx.x;
  const int j = tid & 511;     // gate index
  const int s = tid >> 9;      // k-half (0: h[0..63], 1: h[64..127])

  // pack this thread's 64 weights into 32 f16x2 dwords (32 VGPRs)
  const float2* __restrict__ Wr = (const float2*)(Whh_f + j * 128 + s * 64);
#define LW(k) pk_f16(Wr[k].x, Wr[k].y)
  unsigned w0  = LW(0),  w1  = LW(1),  w2  = LW(2),  w3  = LW(3);
  unsigned w4  = LW(4),  w5  = LW(5),  w6  = LW(6),  w7  = LW(7);
  unsigned w8  = LW(8),  w9  = LW(9),  w10 = LW(10), w11 = LW(11);
  unsigned w12 = LW(12), w13 = LW(13), w14 = LW(14), w15 = LW(15);
  unsigned w16 = LW(16), w17 = LW(17), w18 = LW(18), w19 = LW(19);
  unsigned w20 = LW(20), w21 = LW(21), w22 = LW(22), w23 = LW(23);
  unsigned w24 = LW(24), w25 = LW(25), w26 = LW(26), w27 = LW(27);
  unsigned w28 = LW(28), w29 = LW(29), w30 = LW(30), w31 = LW(31);
#undef LW
  // keep-alive pins (block load-sinking into the loop)
  asm volatile("" : "+v"(w0),  "+v"(w1),  "+v"(w2),  "+v"(w3),
                    "+v"(w4),  "+v"(w5),  "+v"(w6),  "+v"(w7),
                    "+v"(w8),  "+v"(w9),  "+v"(w10), "+v"(w11),
                    "+v"(w12), "+v"(w13), "+v"(w14), "+v"(w15));
  asm volatile("" : "+v"(w16), "+v"(w17), "+v"(w18), "+v"(w19),
                    "+v"(w20), "+v"(w21), "+v"(w22), "+v"(w23),
                    "+v"(w24), "+v"(w25), "+v"(w26), "+v"(w27),
                    "+v"(w28), "+v"(w29), "+v"(w30), "+v"(w31));

  float c = 0.f;
  if (tid < 128) h_s[tid] = 0.f;
  if (tid < 64) h16_s[tid] = 0u;
  __syncthreads();

  float zcur = (s == 0) ? Z[j] : 0.f;   // biases folded into Z
  const u32x4* hr = (const u32x4*)h16_s + s * 8;   // 8 chunks = 32 dwords = 64 f16
  for (int t = 0; t < TT; ++t) {
    const float znext = (s == 0 && t < TT - 1) ? Z[(t + 1) * 512 + j] : 0.f;
    float a0 = zcur, a1 = 0.f, a2 = 0.f, a3 = 0.f;
#define DOTQ(q, wa, wb, wc, wd) { const u32x4 hv = hr[q]; \
    a0 = fdot2u(hv.x, wa, a0); a1 = fdot2u(hv.y, wb, a1); \
    a2 = fdot2u(hv.z, wc, a2); a3 = fdot2u(hv.w, wd, a3); }
    DOTQ(0, w0,  w1,  w2,  w3)
    DOTQ(1, w4,  w5,  w6,  w7)
    __builtin_amdgcn_sched_barrier(0);   // cap in-flight ds_reads
    DOTQ(2, w8,  w9,  w10, w11)
    DOTQ(3, w12, w13, w14, w15)
    __builtin_amdgcn_sched_barrier(0);
    DOTQ(4, w16, w17, w18, w19)
    DOTQ(5, w20, w21, w22, w23)
    __builtin_amdgcn_sched_barrier(0);
    DOTQ(6, w24, w25, w26, w27)
    DOTQ(7, w28, w29, w30, w31)
#undef DOTQ
    p_s[tid] = (a0 + a1) + (a2 + a3);
    __syncthreads();
    if (tid < 128) {
      const float gi = p_s[tid]       + p_s[512 + tid];
      const float gf = p_s[128 + tid] + p_s[640 + tid];
      const float gg = p_s[256 + tid] + p_s[768 + tid];
      const float go = p_s[384 + tid] + p_s[896 + tid];
      c = sigm(gf) * c + sigm(gi) * tanh_fast(gg);
      const float hnew = sigm(go) * tanh_fast(c);
      h_s[tid] = hnew;
      const float hnb = __shfl_xor(hnew, 1, 64);       // neighbor's h
      if (!(tid & 1)) h16_s[tid >> 1] = pk_f16(hnew, hnb);
    }
    __syncthreads();
    zcur = znext;
  }

  // backward LSTM, first step only (h=c=0): elementwise on Zb
  if (tid < 128) {
    const float gi = Zb[tid], gg = Zb[256 + tid], go = Zb[384 + tid];
    const float cb = sigm(gi) * tanh_fast(gg);
    hb_s[tid] = sigm(go) * tanh_fast(cb);
  }
  __syncthreads();

  // out = sigmoid(concat(h_f, h_b) · Wo + bo)
  float v = 0.f;
  if (tid < 128) v = h_s[tid] * Wo[tid];
  else if (tid < 256) v = hb_s[tid - 128] * Wo[tid];
  v = wave_sum64(v);
  if ((tid & 63) == 0) red_s[tid >> 6] = v;
  __syncthreads();
  if (tid == 0) {
    float sum = bo[0];
#pragma unroll
    for (int k = 0; k < 16; ++k) sum += red_s[k];
    out[0] = 1.f / (1.f + __expf(-sum));
  }
}

extern "C" void kernel_launch(void* const* d_in, const int* in_sizes, int n_in,
                              void* d_out, int out_size, void* d_ws, size_t ws_size,
                              hipStream_t stream) {
  const float* x       = (const float*)d_in[0];
  // d_in[1] = edge_index (int32) — complete digraph, indexed analytically
  const float* ea      = (const float*)d_in[2];
  const float* W1      = (const float*)d_in[3];
  const float* a_src1  = (const float*)d_in[4];
  const float* a_dst1  = (const float*)d_in[5];
  const float* We1     = (const float*)d_in[6];
  const float* a_edge1 = (const float*)d_in[7];
  const float* b1      = (const float*)d_in[8];
  const float* W2      = (const float*)d_in[9];
  const float* a_src2  = (const float*)d_in[10];
  const float* a_dst2  = (const float*)d_in[11];
  const float* We2     = (const float*)d_in[12];
  const float* a_edge2 = (const float*)d_in[13];
  const float* b2      = (const float*)d_in[14];
  const float* Wg      = (const float*)d_in[15];
  const float* bg      = (const float*)d_in[16];
  const float* Wih_f   = (const float*)d_in[17];
  const float* Whh_f   = (const float*)d_in[18];
  const float* bih_f   = (const float*)d_in[19];
  const float* bhh_f   = (const float*)d_in[20];
  const float* Wih_b   = (const float*)d_in[21];
  // d_in[22] = Whh_b — unused: backward LSTM contributes only its first step (h=0)
  const float* bih_b   = (const float*)d_in[23];
  const float* bhh_b   = (const float*)d_in[24];
  const float* Wo      = (const float*)d_in[25];
  const float* bo      = (const float*)d_in[26];
  float* out = (float*)d_out;

  float* embs = (float*)d_ws;            // 256*256 floats
  float* Z    = embs + 256 * 256;        // 256*512 floats
  float* Zb   = Z + 256 * 512;           // 512 floats

  gnn_kernel<<<256, 512, 0, stream>>>(x, ea, W1, a_src1, a_dst1, We1, a_edge1, b1,
                                      W2, a_src2, a_dst2, We2, a_edge2, b2, Wg, bg, embs);
  zproj_kernel<<<257, 512, 0, stream>>>(embs, Wih_f, bih_f, bhh_f, Wih_b, bih_b, bhh_b, Z, Zb);
  lstm_kernel<<<1, 1024, 0, stream>>>(Z, Zb, Whh_f, Wo, bo, out);
}

// Round 8
// 282.384 us; speedup vs baseline: 1.2890x; 1.0788x over previous
//
#include <hip/hip_runtime.h>
#include <math.h>

#define NN 64      // nodes
#define TT 256     // frames
#define FF 13      // input features
#define EE 4032    // edges (complete digraph)
#define PP 128     // pooling channels / GAT1 out
#define HH 128     // hidden

typedef float f32x4 __attribute__((ext_vector_type(4)));
typedef _Float16 f16x2 __attribute__((ext_vector_type(2)));

__device__ __forceinline__ float wave_max64(float v) {
#pragma unroll
  for (int off = 32; off > 0; off >>= 1) v = fmaxf(v, __shfl_xor(v, off, 64));
  return v;
}
__device__ __forceinline__ float wave_sum64(float v) {
#pragma unroll
  for (int off = 32; off > 0; off >>= 1) v += __shfl_xor(v, off, 64);
  return v;
}
__device__ __forceinline__ float sigm(float x) { return 1.f / (1.f + __expf(-x)); }
__device__ __forceinline__ float tanh_fast(float x) { return 1.f - 2.f / (__expf(2.f * x) + 1.f); }

// pack two fp32 -> one dword of two f16 (round-toward-zero HW op)
__device__ __forceinline__ unsigned pk_f16(float lo, float hi) {
  unsigned u;
  asm("v_cvt_pkrtz_f16_f32 %0, %1, %2" : "=v"(u) : "v"(lo), "v"(hi));
  return u;
}

// fp32 += dot2(f16x2, f16x2)  -- v_dot2_f32_f16 (fp32 accumulate)
__device__ __forceinline__ float fdot2u(unsigned h, unsigned w, float acc) {
#if __has_builtin(__builtin_amdgcn_fdot2)
  return __builtin_amdgcn_fdot2(__builtin_bit_cast(f16x2, h),
                                __builtin_bit_cast(f16x2, w), acc, false);
#else
  const f16x2 a = __builtin_bit_cast(f16x2, h);
  const f16x2 b = __builtin_bit_cast(f16x2, w);
  return acc + (float)a.x * (float)b.x + (float)a.y * (float)b.y;
#endif
}

// rotate within 16-lane rows: dst[i] = src[(i-1)&15]  (row_ror:1 = 0x121)
// Direction per the canonical GCN row_shr reduction idiom (dst[i]=src[i-n]).
__device__ __forceinline__ float ror1(float x) {
  return __builtin_bit_cast(float, __builtin_amdgcn_mov_dpp(
      __builtin_bit_cast(int, x), 0x121, 0xF, 0xF, true));
}
// quad_perm [1,0,3,2]: neighbor across lane-bit0 (VALU, replaces shfl_xor DS op)
__device__ __forceinline__ float qswap1(float x) {
  return __builtin_bit_cast(float, __builtin_amdgcn_mov_dpp(
      __builtin_bit_cast(int, x), 0xB1, 0xF, 0xF, true));
}

// ---------------------------------------------------------------------------
// Per-frame GNN: GAT1 (4 heads) -> relu -> GAT2 (1 head) -> relu ->
// attention-pool + max-pool -> embs[t][256]
// One block per frame, 512 threads (8 waves). Complete-graph edge indexing:
// edge (s->d) has id j = s*63 + (d<s ? d : d-1)  [np.nonzero(~eye) order].
// ---------------------------------------------------------------------------
__global__ __launch_bounds__(512, 2)
void gnn_kernel(const float* __restrict__ x, const float* __restrict__ ea_g,
                const float* __restrict__ W1, const float* __restrict__ a_src1,
                const float* __restrict__ a_dst1, const float* __restrict__ We1,
                const float* __restrict__ a_edge1, const float* __restrict__ b1,
                const float* __restrict__ W2, const float* __restrict__ a_src2,
                const float* __restrict__ a_dst2, const float* __restrict__ We2,
                const float* __restrict__ a_edge2, const float* __restrict__ b2,
                const float* __restrict__ Wg, const float* __restrict__ bg,
                float* __restrict__ embs)
{
  __shared__ float x_s[NN * FF];
  __shared__ float W1_s[FF * PP];
  __shared__ float ea_s[EE];
  __shared__ float hA_s[NN * PP];   // h1 (GAT1 projected), later p2 (GAT2 projected)
  __shared__ float hB_s[NN * PP];   // relu(GAT1 out), later relu(GAT2 out)
  __shared__ float as1_s[NN * 4];
  __shared__ float ad1_s[NN * 4];
  __shared__ float asrc1_s[PP], adst1_s[PP], asrc2_s[PP], adst2_s[PP];
  __shared__ float b1_s[PP], b2_s[PP], Wg_s[PP];
  __shared__ float as2_s[NN], ad2_s[NN];
  __shared__ float coef_s[8 * 64 * 4];
  __shared__ float wed_s[8];
  __shared__ float attn_s[NN];

  const int tid = threadIdx.x;
  const int t = blockIdx.x;
  const int wave = tid >> 6, lane = tid & 63;

  // stage inputs
  for (int i = tid; i < NN * FF; i += 512) x_s[i] = x[t * NN * FF + i];
  for (int i = tid; i < FF * PP; i += 512) W1_s[i] = W1[i];
  for (int i = tid; i < EE; i += 512) ea_s[i] = ea_g[t * EE + i];
  if (tid < PP) {
    asrc1_s[tid] = a_src1[tid]; adst1_s[tid] = a_dst1[tid];
    asrc2_s[tid] = a_src2[tid]; adst2_s[tid] = a_dst2[tid];
    b1_s[tid] = b1[tid]; b2_s[tid] = b2[tid]; Wg_s[tid] = Wg[tid];
  }
  if (tid >= 128 && tid < 132) {   // wedot1[h] = sum_c We1[h,c]*a_edge1[h,c]
    const int h = tid - 128;
    float acc = 0.f;
    for (int c = 0; c < 32; ++c) acc += We1[h * 32 + c] * a_edge1[h * 32 + c];
    wed_s[h] = acc;
  }
  if (tid == 132) {                // wedot2 = dot(We2, a_edge2)
    float acc = 0.f;
    for (int c = 0; c < 128; ++c) acc += We2[c] * a_edge2[c];
    wed_s[4] = acc;
  }
  __syncthreads();

  // h1 = x @ W1  -> hA  (8192 outputs, 16/thread)
  {
    const int c = tid & 127, ib = tid >> 7;
    for (int q = 0; q < 16; ++q) {
      const int i = ib * 16 + q;
      float acc = 0.f;
#pragma unroll
      for (int f = 0; f < FF; ++f) acc += x_s[i * FF + f] * W1_s[f * PP + c];
      hA_s[i * PP + c] = acc;
    }
  }
  __syncthreads();

  // per-node attention dots: as1[i][h], ad1[i][h]
  {
    const int half = tid >> 8;          // 0: src dots, 1: dst dots
    const int tt2 = tid & 255;
    const int i = tt2 >> 2, h = tt2 & 3;
    const float* aw = half ? adst1_s : asrc1_s;
    float acc = 0.f;
    for (int cc = 0; cc < 32; ++cc) {
      const int c = (cc + tid) & 31;    // rotation: LDS bank-conflict-free
      acc += hA_s[i * PP + h * 32 + c] * aw[h * 32 + c];
    }
    if (half) ad1_s[i * 4 + h] = acc; else as1_s[i * 4 + h] = acc;
  }
  __syncthreads();

  // GAT1 aggregation: each wave owns dst d = kk*8+wave; lanes 0..62 = srcs
  for (int kk = 0; kk < 8; ++kk) {
    const int d = kk * 8 + wave;
    {
      float a0, a1, a2, a3;
      if (lane < 63) {
        const int s = lane + (lane >= d ? 1 : 0);
        const int j = s * 63 + (d < s ? d : d - 1);
        const float ev = ea_s[j];
        a0 = as1_s[s * 4 + 0] + ad1_s[d * 4 + 0] + ev * wed_s[0];
        a1 = as1_s[s * 4 + 1] + ad1_s[d * 4 + 1] + ev * wed_s[1];
        a2 = as1_s[s * 4 + 2] + ad1_s[d * 4 + 2] + ev * wed_s[2];
        a3 = as1_s[s * 4 + 3] + ad1_s[d * 4 + 3] + ev * wed_s[3];
        a0 = a0 > 0.f ? a0 : 0.2f * a0;
        a1 = a1 > 0.f ? a1 : 0.2f * a1;
        a2 = a2 > 0.f ? a2 : 0.2f * a2;
        a3 = a3 > 0.f ? a3 : 0.2f * a3;
      } else { a0 = a1 = a2 = a3 = -1e30f; }
      const float m0 = wave_max64(a0), m1 = wave_max64(a1);
      const float m2 = wave_max64(a2), m3 = wave_max64(a3);
      const float p0 = (lane < 63) ? __expf(a0 - m0) : 0.f;
      const float p1 = (lane < 63) ? __expf(a1 - m1) : 0.f;
      const float p2 = (lane < 63) ? __expf(a2 - m2) : 0.f;
      const float p3 = (lane < 63) ? __expf(a3 - m3) : 0.f;
      const float s0 = wave_sum64(p0), s1 = wave_sum64(p1);
      const float s2 = wave_sum64(p2), s3 = wave_sum64(p3);
      float* cw = &coef_s[(wave * 64 + lane) * 4];
      cw[0] = p0 / (s0 + 1e-16f);
      cw[1] = p1 / (s1 + 1e-16f);
      cw[2] = p2 / (s2 + 1e-16f);
      cw[3] = p3 / (s3 + 1e-16f);
    }
    __syncthreads();
    {
      const int c0 = lane * 2;
      const int hh = c0 >> 5;
      float acc0 = 0.f, acc1 = 0.f;
      const float* cf = &coef_s[wave * 64 * 4 + hh];
      for (int s = 0; s < 63; ++s) {
        const int sn = s + (s >= d ? 1 : 0);
        const float cv = cf[s * 4];
        const float2 hv = *(const float2*)&hA_s[sn * PP + c0];
        acc0 += cv * hv.x; acc1 += cv * hv.y;
      }
      hB_s[d * PP + c0]     = fmaxf(acc0 + b1_s[c0], 0.f);
      hB_s[d * PP + c0 + 1] = fmaxf(acc1 + b1_s[c0 + 1], 0.f);
    }
    __syncthreads();
  }

  // p2 = relu(gat1) @ W2 -> hA (reuse; h1 dead).  W2 streamed from L2.
  {
    const int c = tid & 127, ib = tid >> 7;
    float acc[16];
#pragma unroll
    for (int q = 0; q < 16; ++q) acc[q] = 0.f;
    for (int f0 = 0; f0 < 128; f0 += 4) {
      const float w0 = W2[(f0 + 0) * PP + c];
      const float w1 = W2[(f0 + 1) * PP + c];
      const float w2 = W2[(f0 + 2) * PP + c];
      const float w3 = W2[(f0 + 3) * PP + c];
#pragma unroll
      for (int q = 0; q < 16; ++q) {
        const float4 hv = *(const float4*)&hB_s[(ib * 16 + q) * PP + f0];
        acc[q] += hv.x * w0 + hv.y * w1 + hv.z * w2 + hv.w * w3;
      }
    }
#pragma unroll
    for (int q = 0; q < 16; ++q) hA_s[(ib * 16 + q) * PP + c] = acc[q];
  }
  __syncthreads();

  // as2/ad2 node dots
  if (tid < 128) {
    const int i = tid >> 1, sel = tid & 1;
    const float* aw = sel ? adst2_s : asrc2_s;
    float acc = 0.f;
    for (int cc = 0; cc < 128; ++cc) {
      const int c = (cc + tid) & 127;
      acc += hA_s[i * PP + c] * aw[c];
    }
    if (sel) ad2_s[i] = acc; else as2_s[i] = acc;
  }
  __syncthreads();

  // GAT2 aggregation (1 head)
  for (int kk = 0; kk < 8; ++kk) {
    const int d = kk * 8 + wave;
    {
      float a;
      if (lane < 63) {
        const int s = lane + (lane >= d ? 1 : 0);
        const int j = s * 63 + (d < s ? d : d - 1);
        a = as2_s[s] + ad2_s[d] + ea_s[j] * wed_s[4];
        a = a > 0.f ? a : 0.2f * a;
      } else a = -1e30f;
      const float m = wave_max64(a);
      const float p = (lane < 63) ? __expf(a - m) : 0.f;
      const float ssum = wave_sum64(p);
      coef_s[wave * 64 + lane] = p / (ssum + 1e-16f);
    }
    __syncthreads();
    {
      const int c0 = lane * 2;
      float acc0 = 0.f, acc1 = 0.f;
      const float* cf = &coef_s[wave * 64];
      for (int s = 0; s < 63; ++s) {
        const int sn = s + (s >= d ? 1 : 0);
        const float cv = cf[s];
        const float2 hv = *(const float2*)&hA_s[sn * PP + c0];
        acc0 += cv * hv.x; acc1 += cv * hv.y;
      }
      hB_s[d * PP + c0]     = fmaxf(acc0 + b2_s[c0], 0.f);
      hB_s[d * PP + c0 + 1] = fmaxf(acc1 + b2_s[c0 + 1], 0.f);
    }
    __syncthreads();
  }

  // attention pooling (softmax over 64 nodes, wave 0) + max pooling
  if (tid < 64) {
    float acc = 0.f;
    for (int cc = 0; cc < 128; ++cc) {
      const int c = (cc + tid) & 127;
      acc += hB_s[tid * PP + c] * Wg_s[c];
    }
    const float logit = acc + bg[0];
    const float m = wave_max64(logit);
    const float p = __expf(logit - m);
    const float ssum = wave_sum64(p);
    attn_s[tid] = p / ssum;
  }
  __syncthreads();
  if (tid < 128) {
    const int c = tid;
    float acc = 0.f, mx = -1e30f;
    for (int i = 0; i < NN; ++i) {
      const float v = hB_s[i * PP + c];
      acc += attn_s[i] * v;
      mx = fmaxf(mx, v);
    }
    embs[t * 256 + c] = acc;
    embs[t * 256 + 128 + c] = mx;
  }
}

// ---------------------------------------------------------------------------
// Z[t][j] = Wih_f[j,:]·embs[t] + bih_f[j] + bhh_f[j]   (blocks 0..255)
// Zb[j]   = Wih_b[j,:]·embs[255] + bih_b[j] + bhh_b[j] (block 256)
// ---------------------------------------------------------------------------
__global__ __launch_bounds__(512, 2)
void zproj_kernel(const float* __restrict__ embs,
                  const float* __restrict__ Wih_f, const float* __restrict__ bih_f,
                  const float* __restrict__ bhh_f,
                  const float* __restrict__ Wih_b, const float* __restrict__ bih_b,
                  const float* __restrict__ bhh_b,
                  float* __restrict__ Z, float* __restrict__ Zb)
{
  __shared__ float e_s[256];
  const int t = blockIdx.x;
  const int j = threadIdx.x;
  const bool bwd = (t == TT);
  const int tsrc = bwd ? (TT - 1) : t;
  if (j < 256) e_s[j] = embs[tsrc * 256 + j];
  __syncthreads();
  const float* W = bwd ? Wih_b : Wih_f;
  float acc = bwd ? (bih_b[j] + bhh_b[j]) : (bih_f[j] + bhh_f[j]);
  const float4* Wr = (const float4*)(W + j * 256);
  const float4* er = (const float4*)e_s;
#pragma unroll 8
  for (int k = 0; k < 64; ++k) {
    const float4 w = Wr[k];
    const float4 e = er[k];
    acc += w.x * e.x + w.y * e.y + w.z * e.z + w.w * e.w;
  }
  if (bwd) Zb[j] = acc; else Z[t * 512 + j] = acc;
}

// ---------------------------------------------------------------------------
// Forward LSTM recurrence (256 steps, single block of 1024 threads).
// R7 analysis: weights now VGPR-resident (40 VGPR, no scratch), but the
// step is LDS-pipe-bound: 16 waves x 8 ds_read_b128 = 128 DS instrs/step
// (~1536cy) re-broadcasting h to every wave. Fix: systolic ring. Each
// lane reads its OWN 8-byte h-slice once (1 ds_read_b64), and the
// per-gate accumulator rotates through the 16-lane group via
// v_mov_b32_dpp row_ror:1 (VALU pipe, zero DS). Weight regs are indexed
// by the compile-time rotation step: lane m, step r holds weights of
// gate j0+((m-r)&15) for slice m (32 packed-f16 dwords = 32 VGPRs, fits
// the 64-VGPR budget R7 proved works). DS/step: 128 -> 32 instrs.
// ---------------------------------------------------------------------------
__global__ __launch_bounds__(1024)
void lstm_kernel(const float* __restrict__ Z, const float* __restrict__ Zb,
                 const float* __restrict__ Whh_f,
                 const float* __restrict__ Wo, const float* __restrict__ bo,
                 float* __restrict__ out)
{
  __shared__ float h_s[128];
  __shared__ __align__(16) unsigned h16_s[64];  // h packed as 64 f16x2 dwords
  __shared__ float p_s[1024];
  __shared__ float hb_s[128];
  __shared__ float red_s[16];
  const int tid = threadIdx.x;
  const int j = tid & 511;     // this thread's FINAL gate
  const int s = tid >> 9;      // k-half (0: h[0..63], 1: h[64..127])
  const int m = tid & 15;      // slice within 16-lane ring group
  const int j0 = j & ~15;      // ring group's gate base

  // Weights for the ring: at step r this lane MACs for gate j0+((m-r)&15)
  // using h slice m = floats [s*64+4m .. +3] of that gate's Whh row.
  const float* wbase = Whh_f + s * 64 + 4 * m;
#define LWR(r) \
  unsigned wa##r, wb##r; { \
    const float4 v = *(const float4*)(wbase + (j0 + ((m - (r)) & 15)) * 128); \
    wa##r = pk_f16(v.x, v.y); wb##r = pk_f16(v.z, v.w); }
  LWR(0)  LWR(1)  LWR(2)  LWR(3)  LWR(4)  LWR(5)  LWR(6)  LWR(7)
  LWR(8)  LWR(9)  LWR(10) LWR(11) LWR(12) LWR(13) LWR(14) LWR(15)
#undef LWR
  asm volatile("" : "+v"(wa0),  "+v"(wb0),  "+v"(wa1),  "+v"(wb1),
                    "+v"(wa2),  "+v"(wb2),  "+v"(wa3),  "+v"(wb3),
                    "+v"(wa4),  "+v"(wb4),  "+v"(wa5),  "+v"(wb5),
                    "+v"(wa6),  "+v"(wb6),  "+v"(wa7),  "+v"(wb7));
  asm volatile("" : "+v"(wa8),  "+v"(wb8),  "+v"(wa9),  "+v"(wb9),
                    "+v"(wa10), "+v"(wb10), "+v"(wa11), "+v"(wb11),
                    "+v"(wa12), "+v"(wb12), "+v"(wa13), "+v"(wb13),
                    "+v"(wa14), "+v"(wb14), "+v"(wa15), "+v"(wb15));

  float c = 0.f;
  if (tid < 128) h_s[tid] = 0.f;
  if (tid < 64) h16_s[tid] = 0u;
  __syncthreads();

  float zcur = (s == 0) ? Z[j] : 0.f;   // biases folded into Z
  for (int t = 0; t < TT; ++t) {
    const float znext = (s == 0 && t < TT - 1) ? Z[(t + 1) * 512 + j] : 0.f;
    // own slice: h dwords (s*32 + 2m, +1) -- one ds_read_b64, no re-broadcast
    const uint2 hd = *(const uint2*)&h16_s[s * 32 + 2 * m];
    float acc = 0.f;
#define STEP(r) \
    acc = fdot2u(hd.x, wa##r, acc); \
    acc = fdot2u(hd.y, wb##r, acc); \
    acc = ror1(acc);
    STEP(0)  STEP(1)  STEP(2)  STEP(3)  STEP(4)  STEP(5)  STEP(6)  STEP(7)
    STEP(8)  STEP(9)  STEP(10) STEP(11) STEP(12) STEP(13) STEP(14) STEP(15)
#undef STEP
    // after 16 MAC+rotate steps, lane holds the full half-row sum of gate j
    p_s[tid] = acc + zcur;
    __syncthreads();
    if (tid < 128) {
      const float gi = p_s[tid]       + p_s[512 + tid];
      const float gf = p_s[128 + tid] + p_s[640 + tid];
      const float gg = p_s[256 + tid] + p_s[768 + tid];
      const float go = p_s[384 + tid] + p_s[896 + tid];
      c = sigm(gf) * c + sigm(gi) * tanh_fast(gg);
      const float hnew = sigm(go) * tanh_fast(c);
      h_s[tid] = hnew;
      const float hnb = qswap1(hnew);              // neighbor via quad DPP
      if (!(tid & 1)) h16_s[tid >> 1] = pk_f16(hnew, hnb);
    }
    __syncthreads();
    zcur = znext;
  }

  // backward LSTM, first step only (h=c=0): elementwise on Zb
  if (tid < 128) {
    const float gi = Zb[tid], gg = Zb[256 + tid], go = Zb[384 + tid];
    const float cb = sigm(gi) * tanh_fast(gg);
    hb_s[tid] = sigm(go) * tanh_fast(cb);
  }
  __syncthreads();

  // out = sigmoid(concat(h_f, h_b) · Wo + bo)
  float v = 0.f;
  if (tid < 128) v = h_s[tid] * Wo[tid];
  else if (tid < 256) v = hb_s[tid - 128] * Wo[tid];
  v = wave_sum64(v);
  if ((tid & 63) == 0) red_s[tid >> 6] = v;
  __syncthreads();
  if (tid == 0) {
    float sum = bo[0];
#pragma unroll
    for (int k = 0; k < 16; ++k) sum += red_s[k];
    out[0] = 1.f / (1.f + __expf(-sum));
  }
}

extern "C" void kernel_launch(void* const* d_in, const int* in_sizes, int n_in,
                              void* d_out, int out_size, void* d_ws, size_t ws_size,
                              hipStream_t stream) {
  const float* x       = (const float*)d_in[0];
  // d_in[1] = edge_index (int32) — complete digraph, indexed analytically
  const float* ea      = (const float*)d_in[2];
  const float* W1      = (const float*)d_in[3];
  const float* a_src1  = (const float*)d_in[4];
  const float* a_dst1  = (const float*)d_in[5];
  const float* We1     = (const float*)d_in[6];
  const float* a_edge1 = (const float*)d_in[7];
  const float* b1      = (const float*)d_in[8];
  const float* W2      = (const float*)d_in[9];
  const float* a_src2  = (const float*)d_in[10];
  const float* a_dst2  = (const float*)d_in[11];
  const float* We2     = (const float*)d_in[12];
  const float* a_edge2 = (const float*)d_in[13];
  const float* b2      = (const float*)d_in[14];
  const float* Wg      = (const float*)d_in[15];
  const float* bg      = (const float*)d_in[16];
  const float* Wih_f   = (const float*)d_in[17];
  const float* Whh_f   = (const float*)d_in[18];
  const float* bih_f   = (const float*)d_in[19];
  const float* bhh_f   = (const float*)d_in[20];
  const float* Wih_b   = (const float*)d_in[21];
  // d_in[22] = Whh_b — unused: backward LSTM contributes only its first step (h=0)
  const float* bih_b   = (const float*)d_in[23];
  const float* bhh_b   = (const float*)d_in[24];
  const float* Wo      = (const float*)d_in[25];
  const float* bo      = (const float*)d_in[26];
  float* out = (float*)d_out;

  float* embs = (float*)d_ws;            // 256*256 floats
  float* Z    = embs + 256 * 256;        // 256*512 floats
  float* Zb   = Z + 256 * 512;           // 512 floats

  gnn_kernel<<<256, 512, 0, stream>>>(x, ea, W1, a_src1, a_dst1, We1, a_edge1, b1,
                                      W2, a_src2, a_dst2, We2, a_edge2, b2, Wg, bg, embs);
  zproj_kernel<<<257, 512, 0, stream>>>(embs, Wih_f, bih_f, bhh_f, Wih_b, bih_b, bhh_b, Z, Zb);
  lstm_kernel<<<1, 1024, 0, stream>>>(Z, Zb, Whh_f, Wo, bo, out);
}

// Round 9
// 260.428 us; speedup vs baseline: 1.3976x; 1.0843x over previous
//
#include <hip/hip_runtime.h>
#include <math.h>

#define NN 64      // nodes
#define TT 256     // frames
#define FF 13      // input features
#define EE 4032    // edges (complete digraph)
#define PP 128     // pooling channels / GAT1 out
#define HH 128     // hidden

typedef float f32x4 __attribute__((ext_vector_type(4)));
typedef _Float16 f16x2 __attribute__((ext_vector_type(2)));

__device__ __forceinline__ float wave_sum64(float v) {
#pragma unroll
  for (int off = 32; off > 0; off >>= 1) v += __shfl_xor(v, off, 64);
  return v;
}
__device__ __forceinline__ float sigm(float x) { return 1.f / (1.f + __expf(-x)); }
__device__ __forceinline__ float tanh_fast(float x) { return 1.f - 2.f / (__expf(2.f * x) + 1.f); }

// ---- DPP / lane helpers (VALU pipe; verified direction-safe since reductions
// are commutative over full rotation; R8 passed using the same mov_dpp path) ----
#define ROTF(x, N) __builtin_bit_cast(float, __builtin_amdgcn_mov_dpp( \
    __builtin_bit_cast(int, x), 0x120 + (N), 0xF, 0xF, true))
__device__ __forceinline__ float rdlane(float v, int l) {
  return __builtin_bit_cast(float, __builtin_amdgcn_readlane(__builtin_bit_cast(int, v), l));
}
// full-wave max/sum with ZERO DS instructions: 16-lane rotation reduce (DPP)
// then cross-row combine through v_readlane + scalar ops.
__device__ __forceinline__ float allred_max(float v) {
  v = fmaxf(v, ROTF(v, 1)); v = fmaxf(v, ROTF(v, 2));
  v = fmaxf(v, ROTF(v, 4)); v = fmaxf(v, ROTF(v, 8));
  return fmaxf(fmaxf(rdlane(v, 0), rdlane(v, 16)),
               fmaxf(rdlane(v, 32), rdlane(v, 48)));
}
__device__ __forceinline__ float allred_sum(float v) {
  v += ROTF(v, 1); v += ROTF(v, 2); v += ROTF(v, 4); v += ROTF(v, 8);
  return (rdlane(v, 0) + rdlane(v, 16)) + (rdlane(v, 32) + rdlane(v, 48));
}

// pack two fp32 -> one dword of two f16 (round-toward-zero HW op)
__device__ __forceinline__ unsigned pk_f16(float lo, float hi) {
  unsigned u;
  asm("v_cvt_pkrtz_f16_f32 %0, %1, %2" : "=v"(u) : "v"(lo), "v"(hi));
  return u;
}
// fp32 += dot2(f16x2, f16x2)
__device__ __forceinline__ float fdot2u(unsigned h, unsigned w, float acc) {
#if __has_builtin(__builtin_amdgcn_fdot2)
  return __builtin_amdgcn_fdot2(__builtin_bit_cast(f16x2, h),
                                __builtin_bit_cast(f16x2, w), acc, false);
#else
  const f16x2 a = __builtin_bit_cast(f16x2, h);
  const f16x2 b = __builtin_bit_cast(f16x2, w);
  return acc + (float)a.x * (float)b.x + (float)a.y * (float)b.y;
#endif
}
__device__ __forceinline__ float ror1(float x) {
  return __builtin_bit_cast(float, __builtin_amdgcn_mov_dpp(
      __builtin_bit_cast(int, x), 0x121, 0xF, 0xF, true));
}
__device__ __forceinline__ float qswap1(float x) {
  return __builtin_bit_cast(float, __builtin_amdgcn_mov_dpp(
      __builtin_bit_cast(int, x), 0xB1, 0xF, 0xF, true));
}

// ---------------------------------------------------------------------------
// Per-frame GNN. One block per frame, 512 threads (8 waves).
// DS-count-optimized (R8 post-mortem: gnn was LDS-pipe-bound):
//  - softmax reductions on DPP+readlane (0 DS)
//  - self-masked 64-src loops (ex[d][d]=0), denominator folded out
//  - weighted-sum: 2 dsts/wave, 4ch/lane b128 hv reads, coef [dst][h][s]
//    stride-68 (16B aligned, conflict-free) read b128 over 4 srcs
//  - W2 GEMM 4x4 register-blocked, weights streamed from global (VMEM pipe)
// ---------------------------------------------------------------------------
__global__ __launch_bounds__(512, 2)
void gnn_kernel(const float* __restrict__ x, const float* __restrict__ ea_g,
                const float* __restrict__ W1, const float* __restrict__ a_src1,
                const float* __restrict__ a_dst1, const float* __restrict__ We1,
                const float* __restrict__ a_edge1, const float* __restrict__ b1,
                const float* __restrict__ W2, const float* __restrict__ a_src2,
                const float* __restrict__ a_dst2, const float* __restrict__ We2,
                const float* __restrict__ a_edge2, const float* __restrict__ b2,
                const float* __restrict__ Wg, const float* __restrict__ bg,
                float* __restrict__ embs)
{
  __shared__ float x_s[NN * FF];
  __shared__ float W1_s[FF * PP];
  __shared__ float ea_s[EE];
  __shared__ float hA_s[NN * PP];     // h1 proj, later p2 proj
  __shared__ float hB_s[NN * PP];     // relu(GAT1), later relu(GAT2)
  __shared__ float as1_s[4 * NN];     // [head][node]
  __shared__ float ad1_s[4 * NN];
  __shared__ float asrc1_s[PP], adst1_s[PP], asrc2_s[PP], adst2_s[PP];
  __shared__ float b1_s[PP], b2_s[PP], Wg_s[PP];
  __shared__ float as2_s[NN], ad2_s[NN];
  __shared__ __align__(16) float coefA_s[16 * 272];  // [dst&15][head] stride 68
  __shared__ float denA_s[16 * 4];
  __shared__ __align__(16) float coefB_s[16 * 68];
  __shared__ float denB_s[16];
  __shared__ float wed_s[8];
  __shared__ float attn_s[NN];

  const int tid = threadIdx.x;
  const int t = blockIdx.x;
  const int wave = tid >> 6, lane = tid & 63;

  // stage inputs
  for (int i = tid; i < NN * FF; i += 512) x_s[i] = x[t * NN * FF + i];
  for (int i = tid; i < FF * PP; i += 512) W1_s[i] = W1[i];
  for (int i = tid; i < EE; i += 512) ea_s[i] = ea_g[t * EE + i];
  if (tid < PP) {
    asrc1_s[tid] = a_src1[tid]; adst1_s[tid] = a_dst1[tid];
    asrc2_s[tid] = a_src2[tid]; adst2_s[tid] = a_dst2[tid];
    b1_s[tid] = b1[tid]; b2_s[tid] = b2[tid]; Wg_s[tid] = Wg[tid];
  }
  if (tid >= 128 && tid < 132) {
    const int h = tid - 128;
    float acc = 0.f;
    for (int c = 0; c < 32; ++c) acc += We1[h * 32 + c] * a_edge1[h * 32 + c];
    wed_s[h] = acc;
  }
  if (tid == 132) {
    float acc = 0.f;
    for (int c = 0; c < 128; ++c) acc += We2[c] * a_edge2[c];
    wed_s[4] = acc;
  }
  __syncthreads();

  // h1 = x @ W1 -> hA
  {
    const int c = tid & 127, ib = tid >> 7;
    for (int q = 0; q < 16; ++q) {
      const int i = ib * 16 + q;
      float acc = 0.f;
#pragma unroll
      for (int f = 0; f < FF; ++f) acc += x_s[i * FF + f] * W1_s[f * PP + c];
      hA_s[i * PP + c] = acc;
    }
  }
  __syncthreads();

  // per-node attention dots: as1[h][i], ad1[h][i]
  {
    const int half = tid >> 8;
    const int tt2 = tid & 255;
    const int i = tt2 >> 2, h = tt2 & 3;
    const float* aw = half ? adst1_s : asrc1_s;
    float acc = 0.f;
    for (int cc = 0; cc < 32; ++cc) {
      const int c = (cc + tid) & 31;
      acc += hA_s[i * PP + h * 32 + c] * aw[h * 32 + c];
    }
    if (half) ad1_s[h * 64 + i] = acc; else as1_s[h * 64 + i] = acc;
  }
  __syncthreads();

  // ---- GAT1 aggregation: 4 groups of 16 dsts {softmax x2, wsum} ----
  for (int g = 0; g < 4; ++g) {
#pragma unroll
    for (int r = 0; r < 2; ++r) {
      const int d = g * 16 + r * 8 + wave;
      const int dl = d & 15;
      float a0, a1, a2, a3;
      if (lane != d) {
        const int jj = lane * 63 + (d < lane ? d : d - 1);
        const float ev = ea_s[jj];
        a0 = as1_s[0 * 64 + lane] + ad1_s[0 * 64 + d] + ev * wed_s[0];
        a1 = as1_s[1 * 64 + lane] + ad1_s[1 * 64 + d] + ev * wed_s[1];
        a2 = as1_s[2 * 64 + lane] + ad1_s[2 * 64 + d] + ev * wed_s[2];
        a3 = as1_s[3 * 64 + lane] + ad1_s[3 * 64 + d] + ev * wed_s[3];
        a0 = a0 > 0.f ? a0 : 0.2f * a0;
        a1 = a1 > 0.f ? a1 : 0.2f * a1;
        a2 = a2 > 0.f ? a2 : 0.2f * a2;
        a3 = a3 > 0.f ? a3 : 0.2f * a3;
      } else { a0 = a1 = a2 = a3 = -1e30f; }
      const float m0 = allred_max(a0), m1 = allred_max(a1);
      const float m2 = allred_max(a2), m3 = allred_max(a3);
      const float p0 = (lane != d) ? __expf(a0 - m0) : 0.f;
      const float p1 = (lane != d) ? __expf(a1 - m1) : 0.f;
      const float p2 = (lane != d) ? __expf(a2 - m2) : 0.f;
      const float p3 = (lane != d) ? __expf(a3 - m3) : 0.f;
      const float s0 = allred_sum(p0), s1 = allred_sum(p1);
      const float s2 = allred_sum(p2), s3 = allred_sum(p3);
      coefA_s[dl * 272 + 0 * 68 + lane] = p0;
      coefA_s[dl * 272 + 1 * 68 + lane] = p1;
      coefA_s[dl * 272 + 2 * 68 + lane] = p2;
      coefA_s[dl * 272 + 3 * 68 + lane] = p3;
      if (lane == 0) {
        denA_s[dl * 4 + 0] = s0; denA_s[dl * 4 + 1] = s1;
        denA_s[dl * 4 + 2] = s2; denA_s[dl * 4 + 3] = s3;
      }
    }
    __syncthreads();
    {   // weighted sum: wave covers 2 dsts; 4 ch/lane
      const int half = lane >> 5;
      const int dl = wave * 2 + half;
      const int d  = g * 16 + dl;
      const int c0 = (lane & 31) * 4;
      const int hh = c0 >> 5;
      const float* cfb = &coefA_s[dl * 272 + hh * 68];
      float ac0 = 0.f, ac1 = 0.f, ac2 = 0.f, ac3 = 0.f;
#pragma unroll 4
      for (int s = 0; s < 64; s += 4) {
        const float4 cf = *(const float4*)&cfb[s];
        const float4 h0 = *(const float4*)&hA_s[(s + 0) * PP + c0];
        ac0 += cf.x * h0.x; ac1 += cf.x * h0.y; ac2 += cf.x * h0.z; ac3 += cf.x * h0.w;
        const float4 h1v = *(const float4*)&hA_s[(s + 1) * PP + c0];
        ac0 += cf.y * h1v.x; ac1 += cf.y * h1v.y; ac2 += cf.y * h1v.z; ac3 += cf.y * h1v.w;
        const float4 h2v = *(const float4*)&hA_s[(s + 2) * PP + c0];
        ac0 += cf.z * h2v.x; ac1 += cf.z * h2v.y; ac2 += cf.z * h2v.z; ac3 += cf.z * h2v.w;
        const float4 h3v = *(const float4*)&hA_s[(s + 3) * PP + c0];
        ac0 += cf.w * h3v.x; ac1 += cf.w * h3v.y; ac2 += cf.w * h3v.z; ac3 += cf.w * h3v.w;
      }
      const float inv = 1.f / (denA_s[dl * 4 + hh] + 1e-16f);
      const float4 bv = *(const float4*)&b1_s[c0];
      float4 o;
      o.x = fmaxf(ac0 * inv + bv.x, 0.f);
      o.y = fmaxf(ac1 * inv + bv.y, 0.f);
      o.z = fmaxf(ac2 * inv + bv.z, 0.f);
      o.w = fmaxf(ac3 * inv + bv.w, 0.f);
      *(float4*)&hB_s[d * PP + c0] = o;
    }
    __syncthreads();
  }

  // ---- p2 = relu(gat1) @ W2 -> hA : 4i x 4c register-blocked ----
  {
    const int cg = tid & 31, ig = tid >> 5;
    const int c0 = cg * 4, i0 = ig * 4;
    float acc[4][4];
#pragma unroll
    for (int ii = 0; ii < 4; ++ii)
#pragma unroll
      for (int cc = 0; cc < 4; ++cc) acc[ii][cc] = 0.f;
    for (int f0 = 0; f0 < 128; f0 += 4) {
      float4 wv0 = *(const float4*)&W2[(f0 + 0) * PP + c0];
      float4 wv1 = *(const float4*)&W2[(f0 + 1) * PP + c0];
      float4 wv2 = *(const float4*)&W2[(f0 + 2) * PP + c0];
      float4 wv3 = *(const float4*)&W2[(f0 + 3) * PP + c0];
#pragma unroll
      for (int ii = 0; ii < 4; ++ii) {
        const float4 hv = *(const float4*)&hB_s[(i0 + ii) * PP + f0];
        acc[ii][0] += hv.x * wv0.x + hv.y * wv1.x + hv.z * wv2.x + hv.w * wv3.x;
        acc[ii][1] += hv.x * wv0.y + hv.y * wv1.y + hv.z * wv2.y + hv.w * wv3.y;
        acc[ii][2] += hv.x * wv0.z + hv.y * wv1.z + hv.z * wv2.z + hv.w * wv3.z;
        acc[ii][3] += hv.x * wv0.w + hv.y * wv1.w + hv.z * wv2.w + hv.w * wv3.w;
      }
    }
#pragma unroll
    for (int ii = 0; ii < 4; ++ii) {
      float4 o; o.x = acc[ii][0]; o.y = acc[ii][1]; o.z = acc[ii][2]; o.w = acc[ii][3];
      *(float4*)&hA_s[(i0 + ii) * PP + c0] = o;
    }
  }
  __syncthreads();

  // as2/ad2 node dots
  if (tid < 128) {
    const int i = tid >> 1, sel = tid & 1;
    const float* aw = sel ? adst2_s : asrc2_s;
    float acc = 0.f;
    for (int cc = 0; cc < 128; ++cc) {
      const int c = (cc + tid) & 127;
      acc += hA_s[i * PP + c] * aw[c];
    }
    if (sel) ad2_s[i] = acc; else as2_s[i] = acc;
  }
  __syncthreads();

  // ---- GAT2 aggregation (1 head): 4 groups of 16 dsts ----
  for (int g = 0; g < 4; ++g) {
#pragma unroll
    for (int r = 0; r < 2; ++r) {
      const int d = g * 16 + r * 8 + wave;
      const int dl = d & 15;
      float a;
      if (lane != d) {
        const int jj = lane * 63 + (d < lane ? d : d - 1);
        a = as2_s[lane] + ad2_s[d] + ea_s[jj] * wed_s[4];
        a = a > 0.f ? a : 0.2f * a;
      } else a = -1e30f;
      const float m = allred_max(a);
      const float p = (lane != d) ? __expf(a - m) : 0.f;
      const float ssum = allred_sum(p);
      coefB_s[dl * 68 + lane] = p;
      if (lane == 0) denB_s[dl] = ssum;
    }
    __syncthreads();
    {
      const int half = lane >> 5;
      const int dl = wave * 2 + half;
      const int d  = g * 16 + dl;
      const int c0 = (lane & 31) * 4;
      const float* cfb = &coefB_s[dl * 68];
      float ac0 = 0.f, ac1 = 0.f, ac2 = 0.f, ac3 = 0.f;
#pragma unroll 4
      for (int s = 0; s < 64; s += 4) {
        const float4 cf = *(const float4*)&cfb[s];
        const float4 h0 = *(const float4*)&hA_s[(s + 0) * PP + c0];
        ac0 += cf.x * h0.x; ac1 += cf.x * h0.y; ac2 += cf.x * h0.z; ac3 += cf.x * h0.w;
        const float4 h1v = *(const float4*)&hA_s[(s + 1) * PP + c0];
        ac0 += cf.y * h1v.x; ac1 += cf.y * h1v.y; ac2 += cf.y * h1v.z; ac3 += cf.y * h1v.w;
        const float4 h2v = *(const float4*)&hA_s[(s + 2) * PP + c0];
        ac0 += cf.z * h2v.x; ac1 += cf.z * h2v.y; ac2 += cf.z * h2v.z; ac3 += cf.z * h2v.w;
        const float4 h3v = *(const float4*)&hA_s[(s + 3) * PP + c0];
        ac0 += cf.w * h3v.x; ac1 += cf.w * h3v.y; ac2 += cf.w * h3v.z; ac3 += cf.w * h3v.w;
      }
      const float inv = 1.f / (denB_s[dl] + 1e-16f);
      const float4 bv = *(const float4*)&b2_s[c0];
      float4 o;
      o.x = fmaxf(ac0 * inv + bv.x, 0.f);
      o.y = fmaxf(ac1 * inv + bv.y, 0.f);
      o.z = fmaxf(ac2 * inv + bv.z, 0.f);
      o.w = fmaxf(ac3 * inv + bv.w, 0.f);
      *(float4*)&hB_s[d * PP + c0] = o;
    }
    __syncthreads();
  }

  // attention pooling (softmax over 64 nodes, wave 0) + max pooling
  if (tid < 64) {
    float acc = 0.f;
    for (int cc = 0; cc < 128; ++cc) {
      const int c = (cc + tid) & 127;
      acc += hB_s[tid * PP + c] * Wg_s[c];
    }
    const float logit = acc + bg[0];
    const float m = allred_max(logit);
    const float p = __expf(logit - m);
    const float ssum = allred_sum(p);
    attn_s[tid] = p / ssum;
  }
  __syncthreads();
  if (tid < 128) {
    const int c = tid;
    float acc = 0.f, mx = -1e30f;
    for (int i = 0; i < NN; ++i) {
      const float v = hB_s[i * PP + c];
      acc += attn_s[i] * v;
      mx = fmaxf(mx, v);
    }
    embs[t * 256 + c] = acc;
    embs[t * 256 + 128 + c] = mx;
  }
}

// ---------------------------------------------------------------------------
// Z[t][j] and Zb[j] projections (unchanged)
// ---------------------------------------------------------------------------
__global__ __launch_bounds__(512, 2)
void zproj_kernel(const float* __restrict__ embs,
                  const float* __restrict__ Wih_f, const float* __restrict__ bih_f,
                  const float* __restrict__ bhh_f,
                  const float* __restrict__ Wih_b, const float* __restrict__ bih_b,
                  const float* __restrict__ bhh_b,
                  float* __restrict__ Z, float* __restrict__ Zb)
{
  __shared__ float e_s[256];
  const int t = blockIdx.x;
  const int j = threadIdx.x;
  const bool bwd = (t == TT);
  const int tsrc = bwd ? (TT - 1) : t;
  if (j < 256) e_s[j] = embs[tsrc * 256 + j];
  __syncthreads();
  const float* W = bwd ? Wih_b : Wih_f;
  float acc = bwd ? (bih_b[j] + bhh_b[j]) : (bih_f[j] + bhh_f[j]);
  const float4* Wr = (const float4*)(W + j * 256);
  const float4* er = (const float4*)e_s;
#pragma unroll 8
  for (int k = 0; k < 64; ++k) {
    const float4 w = Wr[k];
    const float4 e = er[k];
    acc += w.x * e.x + w.y * e.y + w.z * e.z + w.w * e.w;
  }
  if (bwd) Zb[j] = acc; else Z[t * 512 + j] = acc;
}

// ---------------------------------------------------------------------------
// Forward LSTM recurrence -- R8 version kept byte-identical (196us, weights
// VGPR-resident at 40 VGPR, no scratch). Systolic ring over 16-lane groups.
// ---------------------------------------------------------------------------
__global__ __launch_bounds__(1024)
void lstm_kernel(const float* __restrict__ Z, const float* __restrict__ Zb,
                 const float* __restrict__ Whh_f,
                 const float* __restrict__ Wo, const float* __restrict__ bo,
                 float* __restrict__ out)
{
  __shared__ float h_s[128];
  __shared__ __align__(16) unsigned h16_s[64];
  __shared__ float p_s[1024];
  __shared__ float hb_s[128];
  __shared__ float red_s[16];
  const int tid = threadIdx.x;
  const int j = tid & 511;
  const int s = tid >> 9;
  const int m = tid & 15;
  const int j0 = j & ~15;

  const float* wbase = Whh_f + s * 64 + 4 * m;
#define LWR(r) \
  unsigned wa##r, wb##r; { \
    const float4 v = *(const float4*)(wbase + (j0 + ((m - (r)) & 15)) * 128); \
    wa##r = pk_f16(v.x, v.y); wb##r = pk_f16(v.z, v.w); }
  LWR(0)  LWR(1)  LWR(2)  LWR(3)  LWR(4)  LWR(5)  LWR(6)  LWR(7)
  LWR(8)  LWR(9)  LWR(10) LWR(11) LWR(12) LWR(13) LWR(14) LWR(15)
#undef LWR
  asm volatile("" : "+v"(wa0),  "+v"(wb0),  "+v"(wa1),  "+v"(wb1),
                    "+v"(wa2),  "+v"(wb2),  "+v"(wa3),  "+v"(wb3),
                    "+v"(wa4),  "+v"(wb4),  "+v"(wa5),  "+v"(wb5),
                    "+v"(wa6),  "+v"(wb6),  "+v"(wa7),  "+v"(wb7));
  asm volatile("" : "+v"(wa8),  "+v"(wb8),  "+v"(wa9),  "+v"(wb9),
                    "+v"(wa10), "+v"(wb10), "+v"(wa11), "+v"(wb11),
                    "+v"(wa12), "+v"(wb12), "+v"(wa13), "+v"(wb13),
                    "+v"(wa14), "+v"(wb14), "+v"(wa15), "+v"(wb15));

  float c = 0.f;
  if (tid < 128) h_s[tid] = 0.f;
  if (tid < 64) h16_s[tid] = 0u;
  __syncthreads();

  float zcur = (s == 0) ? Z[j] : 0.f;
  for (int t = 0; t < TT; ++t) {
    const float znext = (s == 0 && t < TT - 1) ? Z[(t + 1) * 512 + j] : 0.f;
    const uint2 hd = *(const uint2*)&h16_s[s * 32 + 2 * m];
    float acc = 0.f;
#define STEP(r) \
    acc = fdot2u(hd.x, wa##r, acc); \
    acc = fdot2u(hd.y, wb##r, acc); \
    acc = ror1(acc);
    STEP(0)  STEP(1)  STEP(2)  STEP(3)  STEP(4)  STEP(5)  STEP(6)  STEP(7)
    STEP(8)  STEP(9)  STEP(10) STEP(11) STEP(12) STEP(13) STEP(14) STEP(15)
#undef STEP
    p_s[tid] = acc + zcur;
    __syncthreads();
    if (tid < 128) {
      const float gi = p_s[tid]       + p_s[512 + tid];
      const float gf = p_s[128 + tid] + p_s[640 + tid];
      const float gg = p_s[256 + tid] + p_s[768 + tid];
      const float go = p_s[384 + tid] + p_s[896 + tid];
      c = sigm(gf) * c + sigm(gi) * tanh_fast(gg);
      const float hnew = sigm(go) * tanh_fast(c);
      h_s[tid] = hnew;
      const float hnb = qswap1(hnew);
      if (!(tid & 1)) h16_s[tid >> 1] = pk_f16(hnew, hnb);
    }
    __syncthreads();
    zcur = znext;
  }

  if (tid < 128) {
    const float gi = Zb[tid], gg = Zb[256 + tid], go = Zb[384 + tid];
    const float cb = sigm(gi) * tanh_fast(gg);
    hb_s[tid] = sigm(go) * tanh_fast(cb);
  }
  __syncthreads();

  float v = 0.f;
  if (tid < 128) v = h_s[tid] * Wo[tid];
  else if (tid < 256) v = hb_s[tid - 128] * Wo[tid];
  v = wave_sum64(v);
  if ((tid & 63) == 0) red_s[tid >> 6] = v;
  __syncthreads();
  if (tid == 0) {
    float sum = bo[0];
#pragma unroll
    for (int k = 0; k < 16; ++k) sum += red_s[k];
    out[0] = 1.f / (1.f + __expf(-sum));
  }
}

extern "C" void kernel_launch(void* const* d_in, const int* in_sizes, int n_in,
                              void* d_out, int out_size, void* d_ws, size_t ws_size,
                              hipStream_t stream) {
  const float* x       = (const float*)d_in[0];
  // d_in[1] = edge_index (int32) — complete digraph, indexed analytically
  const float* ea      = (const float*)d_in[2];
  const float* W1      = (const float*)d_in[3];
  const float* a_src1  = (const float*)d_in[4];
  const float* a_dst1  = (const float*)d_in[5];
  const float* We1     = (const float*)d_in[6];
  const float* a_edge1 = (const float*)d_in[7];
  const float* b1      = (const float*)d_in[8];
  const float* W2      = (const float*)d_in[9];
  const float* a_src2  = (const float*)d_in[10];
  const float* a_dst2  = (const float*)d_in[11];
  const float* We2     = (const float*)d_in[12];
  const float* a_edge2 = (const float*)d_in[13];
  const float* b2      = (const float*)d_in[14];
  const float* Wg      = (const float*)d_in[15];
  const float* bg      = (const float*)d_in[16];
  const float* Wih_f   = (const float*)d_in[17];
  const float* Whh_f   = (const float*)d_in[18];
  const float* bih_f   = (const float*)d_in[19];
  const float* bhh_f   = (const float*)d_in[20];
  const float* Wih_b   = (const float*)d_in[21];
  // d_in[22] = Whh_b — unused: backward LSTM contributes only its first step (h=0)
  const float* bih_b   = (const float*)d_in[23];
  const float* bhh_b   = (const float*)d_in[24];
  const float* Wo      = (const float*)d_in[25];
  const float* bo      = (const float*)d_in[26];
  float* out = (float*)d_out;

  float* embs = (float*)d_ws;            // 256*256 floats
  float* Z    = embs + 256 * 256;        // 256*512 floats
  float* Zb   = Z + 256 * 512;           // 512 floats

  gnn_kernel<<<256, 512, 0, stream>>>(x, ea, W1, a_src1, a_dst1, We1, a_edge1, b1,
                                      W2, a_src2, a_dst2, We2, a_edge2, b2, Wg, bg, embs);
  zproj_kernel<<<257, 512, 0, stream>>>(embs, Wih_f, bih_f, bhh_f, Wih_b, bih_b, bhh_b, Z, Zb);
  lstm_kernel<<<1, 1024, 0, stream>>>(Z, Zb, Whh_f, Wo, bo, out);
}